// Round 5
// baseline (131.625 us; speedup 1.0000x reference)
//
#include <hip/hip_runtime.h>
#include <math.h>

// ---- problem constants ----
#define B 8
#define NWD 32
#define NHD 32
#define NBOX 1024          // NWD*NHD
#define ZWD 8
#define ZID 32
#define KOBJ 48
#define CFEAT 32
#define WRAW 128
#define HRAW 128
#define CR 28
#define CR2 784
#define FAN 25088          // CFEAT*CR2
#define KB 384             // KOBJ*B

// ---- output offsets (floats, concatenated in reference return order) ----
#define OFF_PROB   0
#define OFF_AREA   8192
#define OFF_CFEW   16384
#define OFF_PFEW   16768
#define OFF_BXF    17152
#define OFF_BYF    17536
#define OFF_BWF    17920
#define OFF_BHF    18304
#define OFF_BMASK  18688
#define OFF_BMASKN 6310144
#define OFF_BIMG   12601600
#define OFF_ZWS    18893056
#define OFF_ZWK    18896128
#define OFF_ZIS    18899200
#define OFF_ZIK    18911488

// ---- workspace offsets (floats) ----
#define WS_SMALL 32768                     // KB*1568 = 602112 floats

// ---- enc GEMM tiling (MFMA v4) ----
#define FSPLIT 112
#define FPB 224            // K-slice per block = 8 crop-rows x 28
#define MKB 32             // kb rows per block
#define NKBG 12            // KB/MKB
#define KSTR 232           // LDS row stride in bf16 elems (464B = 29*16B)

typedef __attribute__((ext_vector_type(8))) short bfrag;    // 8 bf16 (4 VGPRs)
typedef __attribute__((ext_vector_type(4))) float f32x4;

__device__ __forceinline__ float sigm(float x){ return 1.0f/(1.0f+expf(-x)); }
__device__ __forceinline__ float softpl(float x){ return fmaxf(x,0.0f) + log1pf(expf(-fabsf(x))); }
__device__ __forceinline__ float ftanh(float x){
  float t = __expf(2.0f*x);
  return 1.0f - __fdividef(2.0f, t + 1.0f);
}
__device__ __forceinline__ unsigned short f2bf(float f){   // RNE f32->bf16
  unsigned u = __float_as_uint(f);
  unsigned r = u + 0x7FFFu + ((u >> 16) & 1u);
  return (unsigned short)(r >> 16);
}
__device__ __forceinline__ unsigned okey(float f){
  unsigned b = __float_as_uint(f);
  return b ^ ((b & 0x80000000u) ? 0xFFFFFFFFu : 0x80000000u);
}

// K1: maps + single-pass rank-based top-48 + gather of all "few" outputs.
__global__ __launch_bounds__(256) void maps_topk_kernel(
    const float* __restrict__ logit, const float* __restrict__ zmu,
    const float* __restrict__ zstd, const float* __restrict__ zeps,
    const float* __restrict__ wz, const float* __restrict__ bz,
    float* __restrict__ out){
  const int b  = blockIdx.x >> 2;
  const int sb = blockIdx.x & 3;
  const int tid = threadIdx.x;
  __shared__ __align__(16) unsigned su[NBOX];
  #pragma unroll
  for (int u = 0; u < 4; u++){
    int j = tid + u*256;
    su[j] = okey(logit[b*NBOX + j]);
  }
  const int n = sb*256 + tid;
  const int w = n >> 5, h = n & 31;
  float acc0=bz[0], acc1=bz[1], acc2=bz[2], acc3=bz[3];
  #pragma unroll
  for(int z=0; z<ZWD; z++){
    int id = ((b*ZWD + z)*NWD + w)*NHD + h;
    float s = zmu[id] + zstd[id]*zeps[id];
    acc0 += s*wz[0*ZWD+z]; acc1 += s*wz[1*ZWD+z];
    acc2 += s*wz[2*ZWD+z]; acc3 += s*wz[3*ZWD+z];
  }
  float tx=sigm(acc0), ty=sigm(acc1), tw=sigm(acc2), th=sigm(acc3);
  float bx = (128.0f*((float)w + tx))/32.0f;
  float by = (128.0f*((float)h + ty))/32.0f;
  float bwv = 10.0f + 30.0f*tw;
  float bhv = 10.0f + 30.0f*th;
  float lg = logit[b*NBOX + n];
  out[OFF_PROB + b*NBOX + n] = sigm(lg);
  out[OFF_AREA + b*NBOX + n] = bwv*bhv;
  __syncthreads();
  const unsigned ui = su[n];
  const uint4* su4 = (const uint4*)su;
  int rank = 0;
  #pragma unroll 4
  for (int jq = 0; jq < NBOX/4; jq++){
    uint4 v = su4[jq];
    int j = jq*4;
    rank += (v.x > ui || (v.x == ui && j   < n)) ? 1 : 0;
    rank += (v.y > ui || (v.y == ui && j+1 < n)) ? 1 : 0;
    rank += (v.z > ui || (v.z == ui && j+2 < n)) ? 1 : 0;
    rank += (v.w > ui || (v.w == ui && j+3 < n)) ? 1 : 0;
  }
  if (rank < KOBJ){
    out[OFF_CFEW + rank*B + b] = lg;
    out[OFF_PFEW + rank*B + b] = sigm(lg);
    out[OFF_BXF  + rank*B + b] = bx;
    out[OFF_BYF  + rank*B + b] = by;
    out[OFF_BWF  + rank*B + b] = bwv;
    out[OFF_BHF  + rank*B + b] = bhv;
    #pragma unroll
    for(int z=0; z<ZWD; z++){
      int id = ((b*ZWD + z)*NWD + w)*NHD + h;
      float mu = zmu[id], sd = zstd[id];
      out[OFF_ZWS + (rank*B+b)*ZWD + z] = mu + sd*zeps[id];
      out[OFF_ZWK + (rank*B+b)*ZWD + z] = 0.5f*(mu*mu + sd*sd) - logf(sd) - 0.5f;
    }
  }
}

// K2 (v4): fused crop sampling (one thread = one (kb, crop-row)) + MFMA GEMM partials.
__global__ __launch_bounds__(256) void enc_kernel(
    const float* __restrict__ feat, const float* __restrict__ wenc,
    const float* __restrict__ outc, float* __restrict__ part){
  __shared__ __align__(16) unsigned short wl[64*KSTR];   // weights [d][k] bf16
  __shared__ __align__(16) unsigned short cl[MKB*KSTR];  // crops  [kb][k] bf16
  __shared__ float rAx[MKB], rSx[MKB], rAy[MKB], rSy[MKB];
  const int tid = threadIdx.x;
  const int kbg = blockIdx.x % NKBG;     // 12 consecutive blocks share one weight slice
  const int fs  = blockIdx.x / NKBG;
  const int kb0 = kbg*MKB;
  if (tid < MKB){
    float bx = outc[OFF_BXF + kb0 + tid];
    float by = outc[OFF_BYF + kb0 + tid];
    float bw = outc[OFF_BWF + kb0 + tid];
    float bh = outc[OFF_BHF + kb0 + tid];
    float sx = bw * (1.0f/(float)CR), sy = bh * (1.0f/(float)CR);
    rSx[tid] = sx; rSy[tid] = sy;
    rAx[tid] = bx - 0.5f*bw + 0.5f*sx - 0.5f;
    rAy[tid] = by - 0.5f*bh + 0.5f*sy - 0.5f;
  }
  __syncthreads();
  const int fc0 = fs*FPB;
  // stage weights: 64 d x 224 k, float4 loads -> bf16x4 packed stores
  #pragma unroll
  for (int u = 0; u < 14; u++){
    int idx = u*256 + tid;
    int dd = idx / 56, q = idx - dd*56;
    float4 w4 = *(const float4*)&wenc[(size_t)dd*FAN + fc0 + q*4];
    unsigned long long pk = (unsigned long long)f2bf(w4.x)
      | ((unsigned long long)f2bf(w4.y) << 16)
      | ((unsigned long long)f2bf(w4.z) << 32)
      | ((unsigned long long)f2bf(w4.w) << 48);
    *(unsigned long long*)&wl[dd*KSTR + q*4] = pk;
  }
  // stage crop samples: thread owns (kb = tid>>3, row-slot r3 = tid&7) -> fixed (c,i), j=0..27
  {
    const int rr = tid >> 3, r3 = tid & 7;
    const int base = fs*8 + r3;               // = (fc0 + r3*28)/28, in [0,896)
    const int c = base / 28, i = base - c*28;
    const int kb = kb0 + rr;
    const float* img = feat + (size_t)((kb & (B-1))*CFEAT + c)*(WRAW*HRAW);
    float x = fmaf((float)i, rSx[rr], rAx[rr]);
    float x0f = floorf(x);
    int x0 = (int)x0f;
    float wx1 = x - x0f, wx0 = 1.0f - wx1;
    if ((unsigned)x0     >= WRAW) wx0 = 0.f;
    if ((unsigned)(x0+1) >= WRAW) wx1 = 0.f;
    const int xo0 = min(max(x0,0),WRAW-1)*HRAW;
    const int xo1 = min(max(x0+1,0),WRAW-1)*HRAW;
    const float Ay = rAy[rr], Sy = rSy[rr];
    unsigned short* crow = &cl[rr*KSTR + r3*28];
    #pragma unroll
    for (int q = 0; q < 28; q += 4){
      unsigned long long pk = 0ull;
      #pragma unroll
      for (int e = 0; e < 4; e++){
        int j = q + e;
        float y = fmaf((float)j, Sy, Ay);
        float y0f = floorf(y);
        int y0 = (int)y0f;
        float wy1 = y - y0f, wy0 = 1.0f - wy1;
        if ((unsigned)y0     >= HRAW) wy0 = 0.f;
        if ((unsigned)(y0+1) >= HRAW) wy1 = 0.f;
        int y0c = min(max(y0,0),HRAW-1);
        int y1c = min(max(y0+1,0),HRAW-1);
        float v = (img[xo0+y0c]*wy0 + img[xo0+y1c]*wy1)*wx0
                + (img[xo1+y0c]*wy0 + img[xo1+y1c]*wy1)*wx1;
        pk |= (unsigned long long)f2bf(v) << (16*e);
      }
      *(unsigned long long*)(crow + q) = pk;
    }
  }
  __syncthreads();
  // MFMA: wave wv handles kb-half h, d-half g (16kb x 32d), 7 k-steps of 32
  const int lane = tid & 63, wv = tid >> 6;
  const int h = wv & 1, g = wv >> 1;
  const int lr = lane & 15, lg = lane >> 4;
  f32x4 acc0 = {0.f,0.f,0.f,0.f}, acc1 = {0.f,0.f,0.f,0.f};
  const unsigned short* arow  = &cl[(h*16 + lr)*KSTR + lg*8];
  const unsigned short* brow0 = &wl[(g*32 + lr)*KSTR + lg*8];
  const unsigned short* brow1 = &wl[(g*32 + 16 + lr)*KSTR + lg*8];
  #pragma unroll
  for (int s = 0; s < 7; s++){
    bfrag a  = *(const bfrag*)(arow  + s*32);
    bfrag b0 = *(const bfrag*)(brow0 + s*32);
    bfrag b1 = *(const bfrag*)(brow1 + s*32);
    acc0 = __builtin_amdgcn_mfma_f32_16x16x32_bf16(a, b0, acc0, 0, 0, 0);
    acc1 = __builtin_amdgcn_mfma_f32_16x16x32_bf16(a, b1, acc1, 0, 0, 0);
  }
  float* dst = part + ((size_t)fs*KB + kb0)*64;
  #pragma unroll
  for (int r = 0; r < 4; r++){
    int row = h*16 + lg*4 + r;
    dst[row*64 + g*32 + lr]      = acc0[r];
    dst[row*64 + g*32 + 16 + lr] = acc1[r];
  }
}

// K3: reduce enc partials + bias -> zi reparam/KL -> dec GEMM + act -> ws_small
__global__ __launch_bounds__(256) void zi_dec_kernel(
    const float* __restrict__ part, const float* __restrict__ benc,
    const float* __restrict__ ieps, const float* __restrict__ wdec,
    const float* __restrict__ bdec, float* __restrict__ out,
    float* __restrict__ ws){
  int kb = blockIdx.x;
  int d = threadIdx.x & 63, seg = threadIdx.x >> 6;
  float s = 0.f;
  for (int f = seg; f < FSPLIT; f += 4)
    s += part[((size_t)f*KB + kb)*64 + d];
  __shared__ float red[4][64];
  __shared__ float zs[ZID];
  __shared__ float cf_s;
  red[seg][d] = s;
  __syncthreads();
  if (threadIdx.x < ZID){
    int dd = threadIdx.x;
    float mu = benc[dd]     + red[0][dd]     + red[1][dd]     + red[2][dd]     + red[3][dd];
    float pe = benc[ZID+dd] + red[0][ZID+dd] + red[1][ZID+dd] + red[2][ZID+dd] + red[3][ZID+dd];
    float sd = softpl(pe) + 1e-4f;
    float zsv = mu + sd*ieps[kb*ZID + dd];
    out[OFF_ZIS + kb*ZID + dd] = zsv;
    out[OFF_ZIK + kb*ZID + dd] = 0.5f*(mu*mu + sd*sd) - logf(sd) - 0.5f;
    zs[dd] = zsv;
  }
  if (threadIdx.x == 0) cf_s = out[OFF_CFEW + kb];
  __syncthreads();
  float cf = cf_s;
  for (int f = threadIdx.x; f < 2*CR2; f += 256){
    float a = bdec[f];
    #pragma unroll
    for (int q = 0; q < 8; q++){
      float4 w4 = *(const float4*)&wdec[f*ZID + q*4];
      a = fmaf(zs[q*4+0], w4.x, a);
      a = fmaf(zs[q*4+1], w4.y, a);
      a = fmaf(zs[q*4+2], w4.z, a);
      a = fmaf(zs[q*4+3], w4.w, a);
    }
    float v = (f < CR2) ? softpl(a) : sigm(a);
    ws[WS_SMALL + (size_t)kb*(2*CR2) + f] = v*cf;
  }
}

// K4: fused uncrop + compose. One thread per (b, pixel); wr[48] in registers.
__global__ __launch_bounds__(256) void uncrop_compose_kernel(
    const float* __restrict__ ws, float* __restrict__ out){
  const int t = blockIdx.x*256 + threadIdx.x;
  const int b = t >> 14, p = t & 16383;
  const int X = p >> 7, Y = p & 127;
  __shared__ float sAx[KOBJ], sSx[KOBJ], sAy[KOBJ], sSy[KOBJ];
  if (threadIdx.x < KOBJ){
    int k = threadIdx.x;
    float bx = out[OFF_BXF + k*B + b], bw = out[OFF_BWF + k*B + b];
    float by = out[OFF_BYF + k*B + b], bh = out[OFF_BHF + k*B + b];
    float ix = __fdividef((float)CR, bw), iy = __fdividef((float)CR, bh);
    sSx[k] = ix; sAx[k] = (0.5f*bw - bx)*ix - 0.5f;
    sSy[k] = iy; sAy[k] = (0.5f*bh - by)*iy - 0.5f;
  }
  __syncthreads();
  const float xc = (float)X + 0.5f, yc = (float)Y + 0.5f;
  float wr[KOBJ];
  float sum = 0.f;
  #pragma unroll
  for (int k = 0; k < KOBJ; k++){
    float x = fmaf(xc, sSx[k], sAx[k]);
    float y = fmaf(yc, sSy[k], sAy[k]);
    const float* sm = ws + WS_SMALL + (size_t)(k*B + b)*(2*CR2);
    float x0f = floorf(x), y0f = floorf(y);
    int x0 = (int)x0f, y0 = (int)y0f;
    float wx1 = x - x0f, wx0 = 1.0f - wx1;
    float wy1 = y - y0f, wy0 = 1.0f - wy1;
    if ((unsigned)x0     >= CR) wx0 = 0.f;
    if ((unsigned)(x0+1) >= CR) wx1 = 0.f;
    if ((unsigned)y0     >= CR) wy0 = 0.f;
    if ((unsigned)(y0+1) >= CR) wy1 = 0.f;
    int x0c = min(max(x0,0),CR-1), x1c = min(max(x0+1,0),CR-1);
    int y0c = min(max(y0,0),CR-1), y1c = min(max(y0+1,0),CR-1);
    const float* r0 = sm + x0c*CR;
    const float* r1 = sm + x1c*CR;
    float v0 = (r0[y0c]*wy0 + r0[y1c]*wy1)*wx0 + (r1[y0c]*wy0 + r1[y1c]*wy1)*wx1;
    const float* q0 = r0 + CR2;
    const float* q1 = r1 + CR2;
    float v1 = (q0[y0c]*wy0 + q0[y1c]*wy1)*wx0 + (q1[y0c]*wy0 + q1[y1c]*wy1)*wx1;
    wr[k] = v0; sum += v0;
    out[OFF_BIMG + (size_t)(k*B + b)*16384 + p] = v1;
  }
  float th = ftanh(sum);
  float inv = 1.0f / fmaxf(sum, 1e-6f);
  #pragma unroll
  for (int k = 0; k < KOBJ; k++){
    size_t o = (size_t)(k*B + b)*16384 + p;
    out[OFF_BMASK  + o] = th * (wr[k] * inv);
    out[OFF_BMASKN + o] = ftanh(wr[k]);
  }
}

extern "C" void kernel_launch(void* const* d_in, const int* in_sizes, int n_in,
                              void* d_out, int out_size, void* d_ws, size_t ws_size,
                              hipStream_t stream) {
  (void)in_sizes; (void)n_in; (void)out_size; (void)ws_size;
  const float* logit = (const float*)d_in[0];
  const float* zmu   = (const float*)d_in[1];
  const float* zstd  = (const float*)d_in[2];
  const float* zeps  = (const float*)d_in[3];
  const float* ieps  = (const float*)d_in[4];
  const float* feat  = (const float*)d_in[5];
  const float* wz    = (const float*)d_in[6];
  const float* bz    = (const float*)d_in[7];
  const float* wenc  = (const float*)d_in[8];
  const float* benc  = (const float*)d_in[9];
  const float* wdec  = (const float*)d_in[10];
  const float* bdec  = (const float*)d_in[11];
  float* out = (float*)d_out;
  float* ws  = (float*)d_ws;
  float* part = out + OFF_BMASK;   // scratch inside big_mask region (2.75M < 6.29M floats), overwritten later

  maps_topk_kernel    <<<B*4, 256, 0, stream>>>(logit, zmu, zstd, zeps, wz, bz, out);
  enc_kernel          <<<NKBG*FSPLIT, 256, 0, stream>>>(feat, wenc, out, part);
  zi_dec_kernel       <<<KB, 256, 0, stream>>>(part, benc, ieps, wdec, bdec, out, ws);
  uncrop_compose_kernel<<<(B*WRAW*HRAW)/256, 256, 0, stream>>>(ws, out);
}

// Round 6
// 103.352 us; speedup vs baseline: 1.2736x; 1.2736x over previous
//
#include <hip/hip_runtime.h>
#include <math.h>

// ---- problem constants ----
#define B 8
#define NWD 32
#define NHD 32
#define NBOX 1024          // NWD*NHD
#define ZWD 8
#define ZID 32
#define KOBJ 48
#define CFEAT 32
#define WRAW 128
#define HRAW 128
#define CR 28
#define CR2 784
#define FAN 25088          // CFEAT*CR2
#define KB 384             // KOBJ*B

// ---- output offsets (floats, concatenated in reference return order) ----
#define OFF_PROB   0
#define OFF_AREA   8192
#define OFF_CFEW   16384
#define OFF_PFEW   16768
#define OFF_BXF    17152
#define OFF_BYF    17536
#define OFF_BWF    17920
#define OFF_BHF    18304
#define OFF_BMASK  18688
#define OFF_BMASKN 6310144
#define OFF_BIMG   12601600
#define OFF_ZWS    18893056
#define OFF_ZWK    18896128
#define OFF_ZIS    18899200
#define OFF_ZIK    18911488

// ---- workspace offsets (floats) ----
#define WS_SMALL 32768                     // KB*1568 = 602112 floats

// ---- scratch inside big_mask output region (6.29M floats, overwritten later) ----
#define SCR_PART 0                         // FSPLIT*KB*64 = 2752512 floats
#define SCR_WBF  2752512                   // FAN*64 bf16 = 802816 floats

// ---- enc GEMM tiling (MFMA v6: B-frags direct from global bf16) ----
#define FSPLIT 112
#define FPB 224            // K-slice per block
#define MKB 32             // kb rows per block
#define KSTR 232           // LDS row stride in bf16 elems (464B = 29*16B)

typedef __attribute__((ext_vector_type(8))) short bfrag;    // 8 bf16 (4 VGPRs)
typedef __attribute__((ext_vector_type(4))) float f32x4;

__device__ __forceinline__ float sigm(float x){ return 1.0f/(1.0f+expf(-x)); }
__device__ __forceinline__ float softpl(float x){ return fmaxf(x,0.0f) + log1pf(expf(-fabsf(x))); }
__device__ __forceinline__ float ftanh(float x){
  float t = __expf(2.0f*x);
  return 1.0f - __fdividef(2.0f, t + 1.0f);
}
__device__ __forceinline__ unsigned short f2bf(float f){   // RNE f32->bf16
  unsigned u = __float_as_uint(f);
  unsigned r = u + 0x7FFFu + ((u >> 16) & 1u);
  return (unsigned short)(r >> 16);
}
__device__ __forceinline__ unsigned okey(float f){
  unsigned b = __float_as_uint(f);
  return b ^ ((b & 0x80000000u) ? 0xFFFFFFFFu : 0x80000000u);
}

// K0: pre-convert wenc (f32) -> bf16, coalesced. 8 elems/thread.
__global__ __launch_bounds__(256) void wconv_kernel(
    const float* __restrict__ wenc, unsigned short* __restrict__ wbf){
  const size_t i0 = ((size_t)blockIdx.x*256 + threadIdx.x)*8;
  float4 a = *(const float4*)&wenc[i0];
  float4 b = *(const float4*)&wenc[i0+4];
  unsigned long long p0 = (unsigned long long)f2bf(a.x)
    | ((unsigned long long)f2bf(a.y) << 16)
    | ((unsigned long long)f2bf(a.z) << 32)
    | ((unsigned long long)f2bf(a.w) << 48);
  unsigned long long p1 = (unsigned long long)f2bf(b.x)
    | ((unsigned long long)f2bf(b.y) << 16)
    | ((unsigned long long)f2bf(b.z) << 32)
    | ((unsigned long long)f2bf(b.w) << 48);
  *(unsigned long long*)&wbf[i0]   = p0;
  *(unsigned long long*)&wbf[i0+4] = p1;
}

// K1: maps + single-pass rank-based top-48 + gather of all "few" outputs.
__global__ __launch_bounds__(256) void maps_topk_kernel(
    const float* __restrict__ logit, const float* __restrict__ zmu,
    const float* __restrict__ zstd, const float* __restrict__ zeps,
    const float* __restrict__ wz, const float* __restrict__ bz,
    float* __restrict__ out){
  const int b  = blockIdx.x >> 2;
  const int sb = blockIdx.x & 3;
  const int tid = threadIdx.x;
  __shared__ __align__(16) unsigned su[NBOX];
  #pragma unroll
  for (int u = 0; u < 4; u++){
    int j = tid + u*256;
    su[j] = okey(logit[b*NBOX + j]);
  }
  const int n = sb*256 + tid;
  const int w = n >> 5, h = n & 31;
  float acc0=bz[0], acc1=bz[1], acc2=bz[2], acc3=bz[3];
  #pragma unroll
  for(int z=0; z<ZWD; z++){
    int id = ((b*ZWD + z)*NWD + w)*NHD + h;
    float s = zmu[id] + zstd[id]*zeps[id];
    acc0 += s*wz[0*ZWD+z]; acc1 += s*wz[1*ZWD+z];
    acc2 += s*wz[2*ZWD+z]; acc3 += s*wz[3*ZWD+z];
  }
  float tx=sigm(acc0), ty=sigm(acc1), tw=sigm(acc2), th=sigm(acc3);
  float bx = (128.0f*((float)w + tx))/32.0f;
  float by = (128.0f*((float)h + ty))/32.0f;
  float bwv = 10.0f + 30.0f*tw;
  float bhv = 10.0f + 30.0f*th;
  float lg = logit[b*NBOX + n];
  out[OFF_PROB + b*NBOX + n] = sigm(lg);
  out[OFF_AREA + b*NBOX + n] = bwv*bhv;
  __syncthreads();
  const unsigned ui = su[n];
  const uint4* su4 = (const uint4*)su;
  int rank = 0;
  #pragma unroll 4
  for (int jq = 0; jq < NBOX/4; jq++){
    uint4 v = su4[jq];
    int j = jq*4;
    rank += (v.x > ui || (v.x == ui && j   < n)) ? 1 : 0;
    rank += (v.y > ui || (v.y == ui && j+1 < n)) ? 1 : 0;
    rank += (v.z > ui || (v.z == ui && j+2 < n)) ? 1 : 0;
    rank += (v.w > ui || (v.w == ui && j+3 < n)) ? 1 : 0;
  }
  if (rank < KOBJ){
    out[OFF_CFEW + rank*B + b] = lg;
    out[OFF_PFEW + rank*B + b] = sigm(lg);
    out[OFF_BXF  + rank*B + b] = bx;
    out[OFF_BYF  + rank*B + b] = by;
    out[OFF_BWF  + rank*B + b] = bwv;
    out[OFF_BHF  + rank*B + b] = bhv;
    #pragma unroll
    for(int z=0; z<ZWD; z++){
      int id = ((b*ZWD + z)*NWD + w)*NHD + h;
      float mu = zmu[id], sd = zstd[id];
      out[OFF_ZWS + (rank*B+b)*ZWD + z] = mu + sd*zeps[id];
      out[OFF_ZWK + (rank*B+b)*ZWD + z] = 0.5f*(mu*mu + sd*sd) - logf(sd) - 0.5f;
    }
  }
}

// K2 (v6): fused crop sampling (bf16 LDS, coalesced idx-strided) + MFMA;
// B-fragments loaded directly from global bf16 weights (zero in-block reuse -> no LDS tile).
__global__ __launch_bounds__(256) void enc_kernel(
    const float* __restrict__ feat, const unsigned short* __restrict__ wbf,
    const float* __restrict__ outc, float* __restrict__ part){
  __shared__ __align__(16) unsigned short cl[MKB*KSTR];  // crops [kb][k] bf16
  __shared__ float rAx[MKB], rSx[MKB], rAy[MKB], rSy[MKB];
  const int tid = threadIdx.x;
  const int fs  = blockIdx.x % FSPLIT;
  const int kb0 = (blockIdx.x / FSPLIT) * MKB;
  if (tid < MKB){
    float bx = outc[OFF_BXF + kb0 + tid];
    float by = outc[OFF_BYF + kb0 + tid];
    float bw = outc[OFF_BWF + kb0 + tid];
    float bh = outc[OFF_BHF + kb0 + tid];
    float sx = bw * (1.0f/(float)CR), sy = bh * (1.0f/(float)CR);
    rSx[tid] = sx; rSy[tid] = sy;
    rAx[tid] = bx - 0.5f*bw + 0.5f*sx - 0.5f;
    rAy[tid] = by - 0.5f*bh + 0.5f*sy - 0.5f;
  }
  __syncthreads();
  const int fc0 = fs*FPB;
  // stage crop samples: 32 kb x 224 k, consecutive tids -> consecutive k (coalesced taps)
  #pragma unroll 4
  for (int u = 0; u < 28; u++){
    int idx = u*256 + tid;
    int rr = idx / FPB, ff = idx - rr*FPB;
    int f = fc0 + ff;
    int c = f / CR2; int p = f - c*CR2;
    int i = p / CR;  int j = p - i*CR;
    int kb = kb0 + rr;
    const float* img = feat + (size_t)((kb & (B-1))*CFEAT + c)*(WRAW*HRAW);
    float x = fmaf((float)i, rSx[rr], rAx[rr]);
    float y = fmaf((float)j, rSy[rr], rAy[rr]);
    float x0f = floorf(x), y0f = floorf(y);
    int x0 = (int)x0f, y0 = (int)y0f;
    float wx1 = x - x0f, wx0 = 1.0f - wx1;
    float wy1 = y - y0f, wy0 = 1.0f - wy1;
    if ((unsigned)x0     >= WRAW) wx0 = 0.f;
    if ((unsigned)(x0+1) >= WRAW) wx1 = 0.f;
    if ((unsigned)y0     >= HRAW) wy0 = 0.f;
    if ((unsigned)(y0+1) >= HRAW) wy1 = 0.f;
    int x0c = min(max(x0,0),WRAW-1), x1c = min(max(x0+1,0),WRAW-1);
    int y0c = min(max(y0,0),HRAW-1), y1c = min(max(y0+1,0),HRAW-1);
    const float* r0p = img + x0c*HRAW;
    const float* r1p = img + x1c*HRAW;
    float v = (r0p[y0c]*wy0 + r0p[y1c]*wy1)*wx0
            + (r1p[y0c]*wy0 + r1p[y1c]*wy1)*wx1;
    cl[rr*KSTR + ff] = f2bf(v);
  }
  __syncthreads();
  // MFMA: wave wv handles kb-half h, d-half g (16kb x 32d), 7 k-steps of 32.
  const int lane = tid & 63, wv = tid >> 6;
  const int h = wv & 1, g = wv >> 1;
  const int lr = lane & 15, lg = lane >> 4;
  f32x4 acc0 = {0.f,0.f,0.f,0.f}, acc1 = {0.f,0.f,0.f,0.f};
  const unsigned short* arow  = &cl[(h*16 + lr)*KSTR + lg*8];
  const unsigned short* bb0 = wbf + (size_t)(g*32 + lr)*FAN + fc0 + lg*8;
  const unsigned short* bb1 = bb0 + (size_t)16*FAN;
  #pragma unroll
  for (int s = 0; s < 7; s++){
    bfrag a  = *(const bfrag*)(arow + s*32);
    bfrag b0 = *(const bfrag*)(bb0  + s*32);
    bfrag b1 = *(const bfrag*)(bb1  + s*32);
    acc0 = __builtin_amdgcn_mfma_f32_16x16x32_bf16(a, b0, acc0, 0, 0, 0);
    acc1 = __builtin_amdgcn_mfma_f32_16x16x32_bf16(a, b1, acc1, 0, 0, 0);
  }
  float* dst = part + ((size_t)fs*KB + kb0)*64;
  #pragma unroll
  for (int r = 0; r < 4; r++){
    int row = h*16 + lg*4 + r;
    dst[row*64 + g*32 + lr]      = acc0[r];
    dst[row*64 + g*32 + 16 + lr] = acc1[r];
  }
}

// K3: reduce enc partials + bias -> zi reparam/KL -> dec GEMM + act -> ws_small
__global__ __launch_bounds__(256) void zi_dec_kernel(
    const float* __restrict__ part, const float* __restrict__ benc,
    const float* __restrict__ ieps, const float* __restrict__ wdec,
    const float* __restrict__ bdec, float* __restrict__ out,
    float* __restrict__ ws){
  int kb = blockIdx.x;
  int d = threadIdx.x & 63, seg = threadIdx.x >> 6;
  float s0=0.f, s1=0.f, s2=0.f, s3=0.f;
  for (int f = seg; f < FSPLIT; f += 16){     // 4 independent chains -> 4 loads in flight
    s0 += part[((size_t)(f   )*KB + kb)*64 + d];
    s1 += part[((size_t)(f+ 4)*KB + kb)*64 + d];
    s2 += part[((size_t)(f+ 8)*KB + kb)*64 + d];
    s3 += part[((size_t)(f+12)*KB + kb)*64 + d];
  }
  __shared__ float red[4][64];
  __shared__ float zs[ZID];
  __shared__ float cf_s;
  red[seg][d] = (s0+s1) + (s2+s3);
  __syncthreads();
  if (threadIdx.x < ZID){
    int dd = threadIdx.x;
    float mu = benc[dd]     + red[0][dd]     + red[1][dd]     + red[2][dd]     + red[3][dd];
    float pe = benc[ZID+dd] + red[0][ZID+dd] + red[1][ZID+dd] + red[2][ZID+dd] + red[3][ZID+dd];
    float sd = softpl(pe) + 1e-4f;
    float zsv = mu + sd*ieps[kb*ZID + dd];
    out[OFF_ZIS + kb*ZID + dd] = zsv;
    out[OFF_ZIK + kb*ZID + dd] = 0.5f*(mu*mu + sd*sd) - logf(sd) - 0.5f;
    zs[dd] = zsv;
  }
  if (threadIdx.x == 0) cf_s = out[OFF_CFEW + kb];
  __syncthreads();
  float cf = cf_s;
  for (int f = threadIdx.x; f < 2*CR2; f += 256){
    float a = bdec[f];
    #pragma unroll
    for (int q = 0; q < 8; q++){
      float4 w4 = *(const float4*)&wdec[f*ZID + q*4];
      a = fmaf(zs[q*4+0], w4.x, a);
      a = fmaf(zs[q*4+1], w4.y, a);
      a = fmaf(zs[q*4+2], w4.z, a);
      a = fmaf(zs[q*4+3], w4.w, a);
    }
    float v = (f < CR2) ? softpl(a) : sigm(a);
    ws[WS_SMALL + (size_t)kb*(2*CR2) + f] = v*cf;
  }
}

// K4: fused uncrop + compose. One thread per (b, pixel); wr[48] in registers.
__global__ __launch_bounds__(256) void uncrop_compose_kernel(
    const float* __restrict__ ws, float* __restrict__ out){
  const int t = blockIdx.x*256 + threadIdx.x;
  const int b = t >> 14, p = t & 16383;
  const int X = p >> 7, Y = p & 127;
  __shared__ float sAx[KOBJ], sSx[KOBJ], sAy[KOBJ], sSy[KOBJ];
  if (threadIdx.x < KOBJ){
    int k = threadIdx.x;
    float bx = out[OFF_BXF + k*B + b], bw = out[OFF_BWF + k*B + b];
    float by = out[OFF_BYF + k*B + b], bh = out[OFF_BHF + k*B + b];
    float ix = __fdividef((float)CR, bw), iy = __fdividef((float)CR, bh);
    sSx[k] = ix; sAx[k] = (0.5f*bw - bx)*ix - 0.5f;
    sSy[k] = iy; sAy[k] = (0.5f*bh - by)*iy - 0.5f;
  }
  __syncthreads();
  const float xc = (float)X + 0.5f, yc = (float)Y + 0.5f;
  float wr[KOBJ];
  float sum = 0.f;
  #pragma unroll
  for (int k = 0; k < KOBJ; k++){
    float x = fmaf(xc, sSx[k], sAx[k]);
    float y = fmaf(yc, sSy[k], sAy[k]);
    const float* sm = ws + WS_SMALL + (size_t)(k*B + b)*(2*CR2);
    float x0f = floorf(x), y0f = floorf(y);
    int x0 = (int)x0f, y0 = (int)y0f;
    float wx1 = x - x0f, wx0 = 1.0f - wx1;
    float wy1 = y - y0f, wy0 = 1.0f - wy1;
    if ((unsigned)x0     >= CR) wx0 = 0.f;
    if ((unsigned)(x0+1) >= CR) wx1 = 0.f;
    if ((unsigned)y0     >= CR) wy0 = 0.f;
    if ((unsigned)(y0+1) >= CR) wy1 = 0.f;
    int x0c = min(max(x0,0),CR-1), x1c = min(max(x0+1,0),CR-1);
    int y0c = min(max(y0,0),CR-1), y1c = min(max(y0+1,0),CR-1);
    const float* r0 = sm + x0c*CR;
    const float* r1 = sm + x1c*CR;
    float v0 = (r0[y0c]*wy0 + r0[y1c]*wy1)*wx0 + (r1[y0c]*wy0 + r1[y1c]*wy1)*wx1;
    const float* q0 = r0 + CR2;
    const float* q1 = r1 + CR2;
    float v1 = (q0[y0c]*wy0 + q0[y1c]*wy1)*wx0 + (q1[y0c]*wy0 + q1[y1c]*wy1)*wx1;
    wr[k] = v0; sum += v0;
    out[OFF_BIMG + (size_t)(k*B + b)*16384 + p] = v1;
  }
  float th = ftanh(sum);
  float inv = 1.0f / fmaxf(sum, 1e-6f);
  #pragma unroll
  for (int k = 0; k < KOBJ; k++){
    size_t o = (size_t)(k*B + b)*16384 + p;
    out[OFF_BMASK  + o] = th * (wr[k] * inv);
    out[OFF_BMASKN + o] = ftanh(wr[k]);
  }
}

extern "C" void kernel_launch(void* const* d_in, const int* in_sizes, int n_in,
                              void* d_out, int out_size, void* d_ws, size_t ws_size,
                              hipStream_t stream) {
  (void)in_sizes; (void)n_in; (void)out_size; (void)ws_size;
  const float* logit = (const float*)d_in[0];
  const float* zmu   = (const float*)d_in[1];
  const float* zstd  = (const float*)d_in[2];
  const float* zeps  = (const float*)d_in[3];
  const float* ieps  = (const float*)d_in[4];
  const float* feat  = (const float*)d_in[5];
  const float* wz    = (const float*)d_in[6];
  const float* bz    = (const float*)d_in[7];
  const float* wenc  = (const float*)d_in[8];
  const float* benc  = (const float*)d_in[9];
  const float* wdec  = (const float*)d_in[10];
  const float* bdec  = (const float*)d_in[11];
  float* out = (float*)d_out;
  float* ws  = (float*)d_ws;
  float* scr = out + OFF_BMASK;                 // scratch inside big_mask region, overwritten later
  float* part = scr + SCR_PART;                 // 2.75M floats
  unsigned short* wbf = (unsigned short*)(scr + SCR_WBF);  // 1.6M bf16 = 0.8M floats

  wconv_kernel        <<<(FAN*64)/(256*8), 256, 0, stream>>>(wenc, wbf);
  maps_topk_kernel    <<<B*4, 256, 0, stream>>>(logit, zmu, zstd, zeps, wz, bz, out);
  enc_kernel          <<<(KB/MKB)*FSPLIT, 256, 0, stream>>>(feat, wbf, out, part);
  zi_dec_kernel       <<<KB, 256, 0, stream>>>(part, benc, ieps, wdec, bdec, out, ws);
  uncrop_compose_kernel<<<(B*WRAW*HRAW)/256, 256, 0, stream>>>(ws, out);
}

// Round 7
// 100.883 us; speedup vs baseline: 1.3047x; 1.0245x over previous
//
#include <hip/hip_runtime.h>
#include <math.h>

// ---- problem constants ----
#define B 8
#define NWD 32
#define NHD 32
#define NBOX 1024          // NWD*NHD
#define ZWD 8
#define ZID 32
#define KOBJ 48
#define CFEAT 32
#define WRAW 128
#define HRAW 128
#define CR 28
#define CR2 784
#define FAN 25088          // CFEAT*CR2
#define KB 384             // KOBJ*B

// ---- output offsets (floats, concatenated in reference return order) ----
#define OFF_PROB   0
#define OFF_AREA   8192
#define OFF_CFEW   16384
#define OFF_PFEW   16768
#define OFF_BXF    17152
#define OFF_BYF    17536
#define OFF_BWF    17920
#define OFF_BHF    18304
#define OFF_BMASK  18688
#define OFF_BMASKN 6310144
#define OFF_BIMG   12601600
#define OFF_ZWS    18893056
#define OFF_ZWK    18896128
#define OFF_ZIS    18899200
#define OFF_ZIK    18911488

// ---- workspace offsets (floats) ----
#define WS_SMALL 32768                     // KB*1568 = 602112 floats

// ---- scratch inside big_mask output region (6.29M floats, overwritten later) ----
#define SCR_PART 0                         // FSPLIT*KB*64 = 2752512 floats
#define SCR_WBF  2752512                   // FAN*64 bf16 = 802816 floats

// ---- enc GEMM tiling (MFMA v7: 16-kb blocks, bf16 LDS weights, 2688 blocks) ----
#define FSPLIT 112
#define FPB 224            // K-slice per block
#define MKB 16             // kb rows per block
#define KSTR 232           // LDS row stride in bf16 elems (464B = 29*16B)

typedef __attribute__((ext_vector_type(8))) short bfrag;    // 8 bf16 (4 VGPRs)
typedef __attribute__((ext_vector_type(4))) float f32x4;

__device__ __forceinline__ float sigm(float x){ return 1.0f/(1.0f+expf(-x)); }
__device__ __forceinline__ float softpl(float x){ return fmaxf(x,0.0f) + log1pf(expf(-fabsf(x))); }
__device__ __forceinline__ float ftanh(float x){
  float t = __expf(2.0f*x);
  return 1.0f - __fdividef(2.0f, t + 1.0f);
}
__device__ __forceinline__ unsigned short f2bf(float f){   // RNE f32->bf16
  unsigned u = __float_as_uint(f);
  unsigned r = u + 0x7FFFu + ((u >> 16) & 1u);
  return (unsigned short)(r >> 16);
}
__device__ __forceinline__ unsigned okey(float f){
  unsigned b = __float_as_uint(f);
  return b ^ ((b & 0x80000000u) ? 0xFFFFFFFFu : 0x80000000u);
}

// K0: pre-convert wenc (f32) -> bf16, coalesced. 8 elems/thread.
__global__ __launch_bounds__(256) void wconv_kernel(
    const float* __restrict__ wenc, unsigned short* __restrict__ wbf){
  const size_t i0 = ((size_t)blockIdx.x*256 + threadIdx.x)*8;
  float4 a = *(const float4*)&wenc[i0];
  float4 b = *(const float4*)&wenc[i0+4];
  unsigned long long p0 = (unsigned long long)f2bf(a.x)
    | ((unsigned long long)f2bf(a.y) << 16)
    | ((unsigned long long)f2bf(a.z) << 32)
    | ((unsigned long long)f2bf(a.w) << 48);
  unsigned long long p1 = (unsigned long long)f2bf(b.x)
    | ((unsigned long long)f2bf(b.y) << 16)
    | ((unsigned long long)f2bf(b.z) << 32)
    | ((unsigned long long)f2bf(b.w) << 48);
  *(unsigned long long*)&wbf[i0]   = p0;
  *(unsigned long long*)&wbf[i0+4] = p1;
}

// K1: maps + single-pass rank-based top-48 + gather of all "few" outputs.
__global__ __launch_bounds__(256) void maps_topk_kernel(
    const float* __restrict__ logit, const float* __restrict__ zmu,
    const float* __restrict__ zstd, const float* __restrict__ zeps,
    const float* __restrict__ wz, const float* __restrict__ bz,
    float* __restrict__ out){
  const int b  = blockIdx.x >> 2;
  const int sb = blockIdx.x & 3;
  const int tid = threadIdx.x;
  __shared__ __align__(16) unsigned su[NBOX];
  #pragma unroll
  for (int u = 0; u < 4; u++){
    int j = tid + u*256;
    su[j] = okey(logit[b*NBOX + j]);
  }
  const int n = sb*256 + tid;
  const int w = n >> 5, h = n & 31;
  float acc0=bz[0], acc1=bz[1], acc2=bz[2], acc3=bz[3];
  #pragma unroll
  for(int z=0; z<ZWD; z++){
    int id = ((b*ZWD + z)*NWD + w)*NHD + h;
    float s = zmu[id] + zstd[id]*zeps[id];
    acc0 += s*wz[0*ZWD+z]; acc1 += s*wz[1*ZWD+z];
    acc2 += s*wz[2*ZWD+z]; acc3 += s*wz[3*ZWD+z];
  }
  float tx=sigm(acc0), ty=sigm(acc1), tw=sigm(acc2), th=sigm(acc3);
  float bx = (128.0f*((float)w + tx))/32.0f;
  float by = (128.0f*((float)h + ty))/32.0f;
  float bwv = 10.0f + 30.0f*tw;
  float bhv = 10.0f + 30.0f*th;
  float lg = logit[b*NBOX + n];
  out[OFF_PROB + b*NBOX + n] = sigm(lg);
  out[OFF_AREA + b*NBOX + n] = bwv*bhv;
  __syncthreads();
  const unsigned ui = su[n];
  const uint4* su4 = (const uint4*)su;
  int rank = 0;
  #pragma unroll 4
  for (int jq = 0; jq < NBOX/4; jq++){
    uint4 v = su4[jq];
    int j = jq*4;
    rank += (v.x > ui || (v.x == ui && j   < n)) ? 1 : 0;
    rank += (v.y > ui || (v.y == ui && j+1 < n)) ? 1 : 0;
    rank += (v.z > ui || (v.z == ui && j+2 < n)) ? 1 : 0;
    rank += (v.w > ui || (v.w == ui && j+3 < n)) ? 1 : 0;
  }
  if (rank < KOBJ){
    out[OFF_CFEW + rank*B + b] = lg;
    out[OFF_PFEW + rank*B + b] = sigm(lg);
    out[OFF_BXF  + rank*B + b] = bx;
    out[OFF_BYF  + rank*B + b] = by;
    out[OFF_BWF  + rank*B + b] = bwv;
    out[OFF_BHF  + rank*B + b] = bhv;
    #pragma unroll
    for(int z=0; z<ZWD; z++){
      int id = ((b*ZWD + z)*NWD + w)*NHD + h;
      float mu = zmu[id], sd = zstd[id];
      out[OFF_ZWS + (rank*B+b)*ZWD + z] = mu + sd*zeps[id];
      out[OFF_ZWK + (rank*B+b)*ZWD + z] = 0.5f*(mu*mu + sd*sd) - logf(sd) - 0.5f;
    }
  }
}

// K2 (v7): fused crop sampling + MFMA. 16-kb tiles, 2688 blocks,
// bf16 weight tile staged from pre-converted wbf (ushort8 loads, no convert).
__global__ __launch_bounds__(256, 4) void enc_kernel(
    const float* __restrict__ feat, const unsigned short* __restrict__ wbf,
    const float* __restrict__ outc, float* __restrict__ part){
  __shared__ __align__(16) unsigned short wl[64*KSTR];   // weights [d][k] bf16
  __shared__ __align__(16) unsigned short cl[MKB*KSTR];  // crops  [kb][k] bf16
  __shared__ float rAx[MKB], rSx[MKB], rAy[MKB], rSy[MKB];
  const int tid = threadIdx.x;
  const int fs  = blockIdx.x % FSPLIT;
  const int kb0 = (blockIdx.x / FSPLIT) * MKB;
  if (tid < MKB){
    float bx = outc[OFF_BXF + kb0 + tid];
    float by = outc[OFF_BYF + kb0 + tid];
    float bw = outc[OFF_BWF + kb0 + tid];
    float bh = outc[OFF_BHF + kb0 + tid];
    float sx = bw * (1.0f/(float)CR), sy = bh * (1.0f/(float)CR);
    rSx[tid] = sx; rSy[tid] = sy;
    rAx[tid] = bx - 0.5f*bw + 0.5f*sx - 0.5f;
    rAy[tid] = by - 0.5f*bh + 0.5f*sy - 0.5f;
  }
  __syncthreads();
  const int fc0 = fs*FPB;
  // stage weights: 64 d x 224 k bf16, 8 elems/thread/iter (already bf16)
  #pragma unroll
  for (int u = 0; u < 7; u++){
    int idx = u*256 + tid;              // 1792 ushort8 groups
    int dd = idx / 28, q = idx - dd*28;
    bfrag w8 = *(const bfrag*)&wbf[(size_t)dd*FAN + fc0 + q*8];
    *(bfrag*)&wl[dd*KSTR + q*8] = w8;
  }
  // stage crop samples: 16 kb x 224 k, consecutive tids -> consecutive k (coalesced taps)
  #pragma unroll 2
  for (int u = 0; u < 14; u++){
    int idx = u*256 + tid;
    int rr = idx / FPB, ff = idx - rr*FPB;
    int f = fc0 + ff;
    int c = f / CR2; int p = f - c*CR2;
    int i = p / CR;  int j = p - i*CR;
    int kb = kb0 + rr;
    const float* img = feat + (size_t)((kb & (B-1))*CFEAT + c)*(WRAW*HRAW);
    float x = fmaf((float)i, rSx[rr], rAx[rr]);
    float y = fmaf((float)j, rSy[rr], rAy[rr]);
    float x0f = floorf(x), y0f = floorf(y);
    int x0 = (int)x0f, y0 = (int)y0f;
    float wx1 = x - x0f, wx0 = 1.0f - wx1;
    float wy1 = y - y0f, wy0 = 1.0f - wy1;
    if ((unsigned)x0     >= WRAW) wx0 = 0.f;
    if ((unsigned)(x0+1) >= WRAW) wx1 = 0.f;
    if ((unsigned)y0     >= HRAW) wy0 = 0.f;
    if ((unsigned)(y0+1) >= HRAW) wy1 = 0.f;
    int x0c = min(max(x0,0),WRAW-1), x1c = min(max(x0+1,0),WRAW-1);
    int y0c = min(max(y0,0),HRAW-1), y1c = min(max(y0+1,0),HRAW-1);
    const float* r0p = img + x0c*HRAW;
    const float* r1p = img + x1c*HRAW;
    float v = (r0p[y0c]*wy0 + r0p[y1c]*wy1)*wx0
            + (r1p[y0c]*wy0 + r1p[y1c]*wy1)*wx1;
    cl[rr*KSTR + ff] = f2bf(v);
  }
  __syncthreads();
  // MFMA: wave wv owns d-range [wv*16, wv*16+16): 16kb x 16d, 7 k-steps of 32.
  const int lane = tid & 63, wv = tid >> 6;
  const int lr = lane & 15, lg = lane >> 4;
  f32x4 acc = {0.f,0.f,0.f,0.f};
  const unsigned short* arow = &cl[lr*KSTR + lg*8];
  const unsigned short* brow = &wl[(wv*16 + lr)*KSTR + lg*8];
  #pragma unroll
  for (int s = 0; s < 7; s++){
    bfrag a = *(const bfrag*)(arow + s*32);
    bfrag b = *(const bfrag*)(brow + s*32);
    acc = __builtin_amdgcn_mfma_f32_16x16x32_bf16(a, b, acc, 0, 0, 0);
  }
  float* dst = part + ((size_t)fs*KB + kb0)*64;
  #pragma unroll
  for (int r = 0; r < 4; r++){
    int row = lg*4 + r;                // kb offset
    dst[row*64 + wv*16 + lr] = acc[r]; // d = wv*16 + lr
  }
}

// K3: reduce enc partials + bias -> zi reparam/KL -> dec GEMM + act -> ws_small
__global__ __launch_bounds__(256) void zi_dec_kernel(
    const float* __restrict__ part, const float* __restrict__ benc,
    const float* __restrict__ ieps, const float* __restrict__ wdec,
    const float* __restrict__ bdec, float* __restrict__ out,
    float* __restrict__ ws){
  int kb = blockIdx.x;
  int d = threadIdx.x & 63, seg = threadIdx.x >> 6;
  float s0=0.f, s1=0.f, s2=0.f, s3=0.f;
  for (int f = seg; f < FSPLIT; f += 16){     // 4 independent chains -> 4 loads in flight
    s0 += part[((size_t)(f   )*KB + kb)*64 + d];
    s1 += part[((size_t)(f+ 4)*KB + kb)*64 + d];
    s2 += part[((size_t)(f+ 8)*KB + kb)*64 + d];
    s3 += part[((size_t)(f+12)*KB + kb)*64 + d];
  }
  __shared__ float red[4][64];
  __shared__ float zs[ZID];
  __shared__ float cf_s;
  red[seg][d] = (s0+s1) + (s2+s3);
  __syncthreads();
  if (threadIdx.x < ZID){
    int dd = threadIdx.x;
    float mu = benc[dd]     + red[0][dd]     + red[1][dd]     + red[2][dd]     + red[3][dd];
    float pe = benc[ZID+dd] + red[0][ZID+dd] + red[1][ZID+dd] + red[2][ZID+dd] + red[3][ZID+dd];
    float sd = softpl(pe) + 1e-4f;
    float zsv = mu + sd*ieps[kb*ZID + dd];
    out[OFF_ZIS + kb*ZID + dd] = zsv;
    out[OFF_ZIK + kb*ZID + dd] = 0.5f*(mu*mu + sd*sd) - logf(sd) - 0.5f;
    zs[dd] = zsv;
  }
  if (threadIdx.x == 0) cf_s = out[OFF_CFEW + kb];
  __syncthreads();
  float cf = cf_s;
  for (int f = threadIdx.x; f < 2*CR2; f += 256){
    float a = bdec[f];
    #pragma unroll
    for (int q = 0; q < 8; q++){
      float4 w4 = *(const float4*)&wdec[f*ZID + q*4];
      a = fmaf(zs[q*4+0], w4.x, a);
      a = fmaf(zs[q*4+1], w4.y, a);
      a = fmaf(zs[q*4+2], w4.z, a);
      a = fmaf(zs[q*4+3], w4.w, a);
    }
    float v = (f < CR2) ? softpl(a) : sigm(a);
    ws[WS_SMALL + (size_t)kb*(2*CR2) + f] = v*cf;
  }
}

// K4: fused uncrop + compose. One thread per (b, pixel); wr[48] in registers.
__global__ __launch_bounds__(256) void uncrop_compose_kernel(
    const float* __restrict__ ws, float* __restrict__ out){
  const int t = blockIdx.x*256 + threadIdx.x;
  const int b = t >> 14, p = t & 16383;
  const int X = p >> 7, Y = p & 127;
  __shared__ float sAx[KOBJ], sSx[KOBJ], sAy[KOBJ], sSy[KOBJ];
  if (threadIdx.x < KOBJ){
    int k = threadIdx.x;
    float bx = out[OFF_BXF + k*B + b], bw = out[OFF_BWF + k*B + b];
    float by = out[OFF_BYF + k*B + b], bh = out[OFF_BHF + k*B + b];
    float ix = __fdividef((float)CR, bw), iy = __fdividef((float)CR, bh);
    sSx[k] = ix; sAx[k] = (0.5f*bw - bx)*ix - 0.5f;
    sSy[k] = iy; sAy[k] = (0.5f*bh - by)*iy - 0.5f;
  }
  __syncthreads();
  const float xc = (float)X + 0.5f, yc = (float)Y + 0.5f;
  float wr[KOBJ];
  float sum = 0.f;
  #pragma unroll
  for (int k = 0; k < KOBJ; k++){
    float x = fmaf(xc, sSx[k], sAx[k]);
    float y = fmaf(yc, sSy[k], sAy[k]);
    const float* sm = ws + WS_SMALL + (size_t)(k*B + b)*(2*CR2);
    float x0f = floorf(x), y0f = floorf(y);
    int x0 = (int)x0f, y0 = (int)y0f;
    float wx1 = x - x0f, wx0 = 1.0f - wx1;
    float wy1 = y - y0f, wy0 = 1.0f - wy1;
    if ((unsigned)x0     >= CR) wx0 = 0.f;
    if ((unsigned)(x0+1) >= CR) wx1 = 0.f;
    if ((unsigned)y0     >= CR) wy0 = 0.f;
    if ((unsigned)(y0+1) >= CR) wy1 = 0.f;
    int x0c = min(max(x0,0),CR-1), x1c = min(max(x0+1,0),CR-1);
    int y0c = min(max(y0,0),CR-1), y1c = min(max(y0+1,0),CR-1);
    const float* r0 = sm + x0c*CR;
    const float* r1 = sm + x1c*CR;
    float v0 = (r0[y0c]*wy0 + r0[y1c]*wy1)*wx0 + (r1[y0c]*wy0 + r1[y1c]*wy1)*wx1;
    const float* q0 = r0 + CR2;
    const float* q1 = r1 + CR2;
    float v1 = (q0[y0c]*wy0 + q0[y1c]*wy1)*wx0 + (q1[y0c]*wy0 + q1[y1c]*wy1)*wx1;
    wr[k] = v0; sum += v0;
    out[OFF_BIMG + (size_t)(k*B + b)*16384 + p] = v1;
  }
  float th = ftanh(sum);
  float inv = 1.0f / fmaxf(sum, 1e-6f);
  #pragma unroll
  for (int k = 0; k < KOBJ; k++){
    size_t o = (size_t)(k*B + b)*16384 + p;
    out[OFF_BMASK  + o] = th * (wr[k] * inv);
    out[OFF_BMASKN + o] = ftanh(wr[k]);
  }
}

extern "C" void kernel_launch(void* const* d_in, const int* in_sizes, int n_in,
                              void* d_out, int out_size, void* d_ws, size_t ws_size,
                              hipStream_t stream) {
  (void)in_sizes; (void)n_in; (void)out_size; (void)ws_size;
  const float* logit = (const float*)d_in[0];
  const float* zmu   = (const float*)d_in[1];
  const float* zstd  = (const float*)d_in[2];
  const float* zeps  = (const float*)d_in[3];
  const float* ieps  = (const float*)d_in[4];
  const float* feat  = (const float*)d_in[5];
  const float* wz    = (const float*)d_in[6];
  const float* bz    = (const float*)d_in[7];
  const float* wenc  = (const float*)d_in[8];
  const float* benc  = (const float*)d_in[9];
  const float* wdec  = (const float*)d_in[10];
  const float* bdec  = (const float*)d_in[11];
  float* out = (float*)d_out;
  float* ws  = (float*)d_ws;
  float* scr = out + OFF_BMASK;                 // scratch inside big_mask region, overwritten later
  float* part = scr + SCR_PART;                 // 2.75M floats
  unsigned short* wbf = (unsigned short*)(scr + SCR_WBF);  // 1.6M bf16 = 0.8M floats

  wconv_kernel        <<<(FAN*64)/(256*8), 256, 0, stream>>>(wenc, wbf);
  maps_topk_kernel    <<<B*4, 256, 0, stream>>>(logit, zmu, zstd, zeps, wz, bz, out);
  enc_kernel          <<<(KB/MKB)*FSPLIT, 256, 0, stream>>>(feat, wbf, out, part);
  zi_dec_kernel       <<<KB, 256, 0, stream>>>(part, benc, ieps, wdec, bdec, out, ws);
  uncrop_compose_kernel<<<(B*WRAW*HRAW)/256, 256, 0, stream>>>(ws, out);
}

// Round 8
// 95.500 us; speedup vs baseline: 1.3783x; 1.0564x over previous
//
#include <hip/hip_runtime.h>
#include <math.h>

// ---- problem constants ----
#define B 8
#define NWD 32
#define NHD 32
#define NBOX 1024          // NWD*NHD
#define ZWD 8
#define ZID 32
#define KOBJ 48
#define CFEAT 32
#define WRAW 128
#define HRAW 128
#define CR 28
#define CR2 784
#define FAN 25088          // CFEAT*CR2
#define KB 384             // KOBJ*B

// ---- output offsets (floats, concatenated in reference return order) ----
#define OFF_PROB   0
#define OFF_AREA   8192
#define OFF_CFEW   16384
#define OFF_PFEW   16768
#define OFF_BXF    17152
#define OFF_BYF    17536
#define OFF_BWF    17920
#define OFF_BHF    18304
#define OFF_BMASK  18688
#define OFF_BMASKN 6310144
#define OFF_BIMG   12601600
#define OFF_ZWS    18893056
#define OFF_ZWK    18896128
#define OFF_ZIS    18899200
#define OFF_ZIK    18911488

// ---- workspace offsets (floats) ----
#define WS_SMALL 32768                     // KB*1568 = 602112 floats

// ---- scratch inside big_mask output region (6.29M floats, overwritten later) ----
#define SCR_PART 0                         // FSPLIT*KB*64 = 2752512 floats
#define SCR_WT   2752512                   // FAN*64 bf16 = 802816 floats (fragment-ordered)

// ---- enc GEMM tiling (MFMA v8: frag-ordered global weights, tap tables) ----
#define FSPLIT 112
#define FPB 224            // K-slice per block
#define MKB 16             // kb rows per block
#define KSTR 232           // LDS row stride in bf16 elems (464B = 29*16B)
#define TAPN (MKB*28)      // 448 tap entries per axis

typedef __attribute__((ext_vector_type(8))) short bfrag;    // 8 bf16 (4 VGPRs)
typedef __attribute__((ext_vector_type(4))) float f32x4;

__device__ __forceinline__ float sigm(float x){ return 1.0f/(1.0f+expf(-x)); }
__device__ __forceinline__ float softpl(float x){ return fmaxf(x,0.0f) + log1pf(expf(-fabsf(x))); }
__device__ __forceinline__ float ftanh(float x){
  float t = __expf(2.0f*x);
  return 1.0f - __fdividef(2.0f, t + 1.0f);
}
__device__ __forceinline__ unsigned short f2bf(float f){   // RNE f32->bf16
  unsigned u = __float_as_uint(f);
  unsigned r = u + 0x7FFFu + ((u >> 16) & 1u);
  return (unsigned short)(r >> 16);
}
__device__ __forceinline__ unsigned okey(float f){
  unsigned b = __float_as_uint(f);
  return b ^ ((b & 0x80000000u) ? 0xFFFFFFFFu : 0x80000000u);
}

// K0 (v2): wenc f32 -> bf16 pre-swizzled to MFMA B-fragment order.
// wt index = (((fs*7 + s)*4 + t)*64 + lane)*8 ; d = t*16+(lane&15), k = fs*224+s*32+(lane>>4)*8
__global__ __launch_bounds__(256) void wconv_kernel(
    const float* __restrict__ wenc, unsigned short* __restrict__ wt){
  const int gid = blockIdx.x*256 + threadIdx.x;   // 200704 total
  const int lane = gid & 63;
  const int rest = gid >> 6;
  const int t = rest & 3;
  const int rest2 = rest >> 2;         // fs*7 + s
  const int s = rest2 % 7;
  const int fs = rest2 / 7;
  const int d = t*16 + (lane & 15);
  const int k0 = fs*FPB + s*32 + (lane >> 4)*8;
  const float* src = wenc + (size_t)d*FAN + k0;
  float4 a = *(const float4*)src;
  float4 b = *(const float4*)(src + 4);
  unsigned long long p0 = (unsigned long long)f2bf(a.x)
    | ((unsigned long long)f2bf(a.y) << 16)
    | ((unsigned long long)f2bf(a.z) << 32)
    | ((unsigned long long)f2bf(a.w) << 48);
  unsigned long long p1 = (unsigned long long)f2bf(b.x)
    | ((unsigned long long)f2bf(b.y) << 16)
    | ((unsigned long long)f2bf(b.z) << 32)
    | ((unsigned long long)f2bf(b.w) << 48);
  unsigned short* dst = wt + (size_t)gid*8;
  *(unsigned long long*)dst       = p0;
  *(unsigned long long*)(dst + 4) = p1;
}

// K1: maps + single-pass rank-based top-48 + gather of all "few" outputs.
__global__ __launch_bounds__(256) void maps_topk_kernel(
    const float* __restrict__ logit, const float* __restrict__ zmu,
    const float* __restrict__ zstd, const float* __restrict__ zeps,
    const float* __restrict__ wz, const float* __restrict__ bz,
    float* __restrict__ out){
  const int b  = blockIdx.x >> 2;
  const int sb = blockIdx.x & 3;
  const int tid = threadIdx.x;
  __shared__ __align__(16) unsigned su[NBOX];
  #pragma unroll
  for (int u = 0; u < 4; u++){
    int j = tid + u*256;
    su[j] = okey(logit[b*NBOX + j]);
  }
  const int n = sb*256 + tid;
  const int w = n >> 5, h = n & 31;
  float acc0=bz[0], acc1=bz[1], acc2=bz[2], acc3=bz[3];
  #pragma unroll
  for(int z=0; z<ZWD; z++){
    int id = ((b*ZWD + z)*NWD + w)*NHD + h;
    float s = zmu[id] + zstd[id]*zeps[id];
    acc0 += s*wz[0*ZWD+z]; acc1 += s*wz[1*ZWD+z];
    acc2 += s*wz[2*ZWD+z]; acc3 += s*wz[3*ZWD+z];
  }
  float tx=sigm(acc0), ty=sigm(acc1), tw=sigm(acc2), th=sigm(acc3);
  float bx = (128.0f*((float)w + tx))/32.0f;
  float by = (128.0f*((float)h + ty))/32.0f;
  float bwv = 10.0f + 30.0f*tw;
  float bhv = 10.0f + 30.0f*th;
  float lg = logit[b*NBOX + n];
  out[OFF_PROB + b*NBOX + n] = sigm(lg);
  out[OFF_AREA + b*NBOX + n] = bwv*bhv;
  __syncthreads();
  const unsigned ui = su[n];
  const uint4* su4 = (const uint4*)su;
  int rank = 0;
  #pragma unroll 4
  for (int jq = 0; jq < NBOX/4; jq++){
    uint4 v = su4[jq];
    int j = jq*4;
    rank += (v.x > ui || (v.x == ui && j   < n)) ? 1 : 0;
    rank += (v.y > ui || (v.y == ui && j+1 < n)) ? 1 : 0;
    rank += (v.z > ui || (v.z == ui && j+2 < n)) ? 1 : 0;
    rank += (v.w > ui || (v.w == ui && j+3 < n)) ? 1 : 0;
  }
  if (rank < KOBJ){
    out[OFF_CFEW + rank*B + b] = lg;
    out[OFF_PFEW + rank*B + b] = sigm(lg);
    out[OFF_BXF  + rank*B + b] = bx;
    out[OFF_BYF  + rank*B + b] = by;
    out[OFF_BWF  + rank*B + b] = bwv;
    out[OFF_BHF  + rank*B + b] = bhv;
    #pragma unroll
    for(int z=0; z<ZWD; z++){
      int id = ((b*ZWD + z)*NWD + w)*NHD + h;
      float mu = zmu[id], sd = zstd[id];
      out[OFF_ZWS + (rank*B+b)*ZWD + z] = mu + sd*zeps[id];
      out[OFF_ZWK + (rank*B+b)*ZWD + z] = 0.5f*(mu*mu + sd*sd) - logf(sd) - 0.5f;
    }
  }
}

// K2 (v8): tap tables in LDS -> lean sampling -> MFMA with B-frags direct from
// fragment-ordered global weights (coalesced 16B/lane, no weight LDS tile).
__global__ __launch_bounds__(256, 8) void enc_kernel(
    const float* __restrict__ feat, const unsigned short* __restrict__ wt,
    const float* __restrict__ outc, float* __restrict__ part){
  __shared__ __align__(16) unsigned short cl[MKB*KSTR];  // crops [kb][k] bf16
  __shared__ float2 wxs[TAPN]; __shared__ int2 xos[TAPN];
  __shared__ float2 wys[TAPN]; __shared__ int2 yos[TAPN];
  __shared__ float rAx[MKB], rSx[MKB], rAy[MKB], rSy[MKB];
  const int tid = threadIdx.x;
  const int fs  = blockIdx.x % FSPLIT;
  const int kb0 = (blockIdx.x / FSPLIT) * MKB;
  if (tid < MKB){
    float bx = outc[OFF_BXF + kb0 + tid];
    float by = outc[OFF_BYF + kb0 + tid];
    float bw = outc[OFF_BWF + kb0 + tid];
    float bh = outc[OFF_BHF + kb0 + tid];
    float sx = bw * (1.0f/(float)CR), sy = bh * (1.0f/(float)CR);
    rSx[tid] = sx; rSy[tid] = sy;
    rAx[tid] = bx - 0.5f*bw + 0.5f*sx - 0.5f;
    rAy[tid] = by - 0.5f*bh + 0.5f*sy - 0.5f;
  }
  __syncthreads();
  // tap tables: 448 x-entries then 448 y-entries
  #pragma unroll
  for (int it = 0; it < 4; it++){
    int idx = it*256 + tid;
    if (idx < 2*TAPN){
      int isy = idx >= TAPN;
      int q = idx - (isy ? TAPN : 0);
      int rr = q / 28, i = q - rr*28;
      float A = isy ? rAy[rr] : rAx[rr];
      float S = isy ? rSy[rr] : rSx[rr];
      float x = fmaf((float)i, S, A);
      float x0f = floorf(x); int x0 = (int)x0f;
      float w1 = x - x0f, w0 = 1.0f - w1;
      if ((unsigned)x0     >= WRAW) w0 = 0.f;
      if ((unsigned)(x0+1) >= WRAW) w1 = 0.f;
      int c0 = min(max(x0,0),WRAW-1), c1 = min(max(x0+1,0),WRAW-1);
      if (isy){ wys[q] = make_float2(w0,w1); yos[q] = make_int2(c0, c1); }
      else    { wxs[q] = make_float2(w0,w1); xos[q] = make_int2(c0*HRAW, c1*HRAW); }
    }
  }
  __syncthreads();
  const int fc0 = fs*FPB;
  // sampling: 16 kb x 224 k, consecutive tids -> consecutive k (coalesced taps)
  #pragma unroll 2
  for (int u = 0; u < 14; u++){
    int idx = u*256 + tid;
    int rr = idx / FPB, ff = idx - rr*FPB;
    int f = fc0 + ff;
    int c = f / CR2; int p = f - c*CR2;
    int i = p / CR;  int j = p - i*CR;
    const float* img = feat + (size_t)(((kb0+rr) & (B-1))*CFEAT + c)*(WRAW*HRAW);
    float2 wx = wxs[rr*28 + i]; int2 xo = xos[rr*28 + i];
    float2 wy = wys[rr*28 + j]; int2 yo = yos[rr*28 + j];
    float v = (img[xo.x+yo.x]*wy.x + img[xo.x+yo.y]*wy.y)*wx.x
            + (img[xo.y+yo.x]*wy.x + img[xo.y+yo.y]*wy.y)*wx.y;
    cl[rr*KSTR + ff] = f2bf(v);
  }
  __syncthreads();
  // MFMA: wave wv owns d-range [wv*16, wv*16+16): 16kb x 16d, 7 k-steps of 32.
  const int lane = tid & 63, wv = tid >> 6;
  const int lr = lane & 15, lg = lane >> 4;
  f32x4 acc = {0.f,0.f,0.f,0.f};
  const unsigned short* arow  = &cl[lr*KSTR + lg*8];
  const unsigned short* bbase = wt + (size_t)fs*14336 + wv*512 + lane*8;
  #pragma unroll
  for (int s = 0; s < 7; s++){
    bfrag a = *(const bfrag*)(arow + s*32);
    bfrag b = *(const bfrag*)(bbase + s*2048);
    acc = __builtin_amdgcn_mfma_f32_16x16x32_bf16(a, b, acc, 0, 0, 0);
  }
  float* dst = part + ((size_t)fs*KB + kb0)*64;
  #pragma unroll
  for (int r = 0; r < 4; r++){
    int row = lg*4 + r;                // kb offset
    dst[row*64 + wv*16 + lr] = acc[r]; // d = wv*16 + lr
  }
}

// K3: reduce enc partials + bias -> zi reparam/KL -> dec GEMM + act -> ws_small
__global__ __launch_bounds__(256) void zi_dec_kernel(
    const float* __restrict__ part, const float* __restrict__ benc,
    const float* __restrict__ ieps, const float* __restrict__ wdec,
    const float* __restrict__ bdec, float* __restrict__ out,
    float* __restrict__ ws){
  int kb = blockIdx.x;
  int d = threadIdx.x & 63, seg = threadIdx.x >> 6;
  float s0=0.f, s1=0.f, s2=0.f, s3=0.f;
  for (int f = seg; f < FSPLIT; f += 16){     // 4 independent chains -> 4 loads in flight
    s0 += part[((size_t)(f   )*KB + kb)*64 + d];
    s1 += part[((size_t)(f+ 4)*KB + kb)*64 + d];
    s2 += part[((size_t)(f+ 8)*KB + kb)*64 + d];
    s3 += part[((size_t)(f+12)*KB + kb)*64 + d];
  }
  __shared__ float red[4][64];
  __shared__ float zs[ZID];
  __shared__ float cf_s;
  red[seg][d] = (s0+s1) + (s2+s3);
  __syncthreads();
  if (threadIdx.x < ZID){
    int dd = threadIdx.x;
    float mu = benc[dd]     + red[0][dd]     + red[1][dd]     + red[2][dd]     + red[3][dd];
    float pe = benc[ZID+dd] + red[0][ZID+dd] + red[1][ZID+dd] + red[2][ZID+dd] + red[3][ZID+dd];
    float sd = softpl(pe) + 1e-4f;
    float zsv = mu + sd*ieps[kb*ZID + dd];
    out[OFF_ZIS + kb*ZID + dd] = zsv;
    out[OFF_ZIK + kb*ZID + dd] = 0.5f*(mu*mu + sd*sd) - logf(sd) - 0.5f;
    zs[dd] = zsv;
  }
  if (threadIdx.x == 0) cf_s = out[OFF_CFEW + kb];
  __syncthreads();
  float cf = cf_s;
  for (int f = threadIdx.x; f < 2*CR2; f += 256){
    float a = bdec[f];
    #pragma unroll
    for (int q = 0; q < 8; q++){
      float4 w4 = *(const float4*)&wdec[f*ZID + q*4];
      a = fmaf(zs[q*4+0], w4.x, a);
      a = fmaf(zs[q*4+1], w4.y, a);
      a = fmaf(zs[q*4+2], w4.z, a);
      a = fmaf(zs[q*4+3], w4.w, a);
    }
    float v = (f < CR2) ? softpl(a) : sigm(a);
    ws[WS_SMALL + (size_t)kb*(2*CR2) + f] = v*cf;
  }
}

// K4: fused uncrop + compose. One thread per (b, pixel); wr[48] in registers.
__global__ __launch_bounds__(256) void uncrop_compose_kernel(
    const float* __restrict__ ws, float* __restrict__ out){
  const int t = blockIdx.x*256 + threadIdx.x;
  const int b = t >> 14, p = t & 16383;
  const int X = p >> 7, Y = p & 127;
  __shared__ float sAx[KOBJ], sSx[KOBJ], sAy[KOBJ], sSy[KOBJ];
  if (threadIdx.x < KOBJ){
    int k = threadIdx.x;
    float bx = out[OFF_BXF + k*B + b], bw = out[OFF_BWF + k*B + b];
    float by = out[OFF_BYF + k*B + b], bh = out[OFF_BHF + k*B + b];
    float ix = __fdividef((float)CR, bw), iy = __fdividef((float)CR, bh);
    sSx[k] = ix; sAx[k] = (0.5f*bw - bx)*ix - 0.5f;
    sSy[k] = iy; sAy[k] = (0.5f*bh - by)*iy - 0.5f;
  }
  __syncthreads();
  const float xc = (float)X + 0.5f, yc = (float)Y + 0.5f;
  float wr[KOBJ];
  float sum = 0.f;
  #pragma unroll
  for (int k = 0; k < KOBJ; k++){
    float x = fmaf(xc, sSx[k], sAx[k]);
    float y = fmaf(yc, sSy[k], sAy[k]);
    const float* sm = ws + WS_SMALL + (size_t)(k*B + b)*(2*CR2);
    float x0f = floorf(x), y0f = floorf(y);
    int x0 = (int)x0f, y0 = (int)y0f;
    float wx1 = x - x0f, wx0 = 1.0f - wx1;
    float wy1 = y - y0f, wy0 = 1.0f - wy1;
    if ((unsigned)x0     >= CR) wx0 = 0.f;
    if ((unsigned)(x0+1) >= CR) wx1 = 0.f;
    if ((unsigned)y0     >= CR) wy0 = 0.f;
    if ((unsigned)(y0+1) >= CR) wy1 = 0.f;
    int x0c = min(max(x0,0),CR-1), x1c = min(max(x0+1,0),CR-1);
    int y0c = min(max(y0,0),CR-1), y1c = min(max(y0+1,0),CR-1);
    const float* r0 = sm + x0c*CR;
    const float* r1 = sm + x1c*CR;
    float v0 = (r0[y0c]*wy0 + r0[y1c]*wy1)*wx0 + (r1[y0c]*wy0 + r1[y1c]*wy1)*wx1;
    const float* q0 = r0 + CR2;
    const float* q1 = r1 + CR2;
    float v1 = (q0[y0c]*wy0 + q0[y1c]*wy1)*wx0 + (q1[y0c]*wy0 + q1[y1c]*wy1)*wx1;
    wr[k] = v0; sum += v0;
    out[OFF_BIMG + (size_t)(k*B + b)*16384 + p] = v1;
  }
  float th = ftanh(sum);
  float inv = 1.0f / fmaxf(sum, 1e-6f);
  #pragma unroll
  for (int k = 0; k < KOBJ; k++){
    size_t o = (size_t)(k*B + b)*16384 + p;
    out[OFF_BMASK  + o] = th * (wr[k] * inv);
    out[OFF_BMASKN + o] = ftanh(wr[k]);
  }
}

extern "C" void kernel_launch(void* const* d_in, const int* in_sizes, int n_in,
                              void* d_out, int out_size, void* d_ws, size_t ws_size,
                              hipStream_t stream) {
  (void)in_sizes; (void)n_in; (void)out_size; (void)ws_size;
  const float* logit = (const float*)d_in[0];
  const float* zmu   = (const float*)d_in[1];
  const float* zstd  = (const float*)d_in[2];
  const float* zeps  = (const float*)d_in[3];
  const float* ieps  = (const float*)d_in[4];
  const float* feat  = (const float*)d_in[5];
  const float* wz    = (const float*)d_in[6];
  const float* bz    = (const float*)d_in[7];
  const float* wenc  = (const float*)d_in[8];
  const float* benc  = (const float*)d_in[9];
  const float* wdec  = (const float*)d_in[10];
  const float* bdec  = (const float*)d_in[11];
  float* out = (float*)d_out;
  float* ws  = (float*)d_ws;
  float* scr = out + OFF_BMASK;                 // scratch inside big_mask region, overwritten later
  float* part = scr + SCR_PART;                 // 2.75M floats
  unsigned short* wt = (unsigned short*)(scr + SCR_WT);  // 1.6M bf16, fragment-ordered

  wconv_kernel        <<<(FAN*64)/(256*8), 256, 0, stream>>>(wenc, wt);
  maps_topk_kernel    <<<B*4, 256, 0, stream>>>(logit, zmu, zstd, zeps, wz, bz, out);
  enc_kernel          <<<(KB/MKB)*FSPLIT, 256, 0, stream>>>(feat, wt, out, part);
  zi_dec_kernel       <<<KB, 256, 0, stream>>>(part, benc, ieps, wdec, bdec, out, ws);
  uncrop_compose_kernel<<<(B*WRAW*HRAW)/256, 256, 0, stream>>>(ws, out);
}

// Round 9
// 95.100 us; speedup vs baseline: 1.3841x; 1.0042x over previous
//
#include <hip/hip_runtime.h>
#include <math.h>

// ---- problem constants ----
#define B 8
#define NWD 32
#define NHD 32
#define NBOX 1024          // NWD*NHD
#define ZWD 8
#define ZID 32
#define KOBJ 48
#define CFEAT 32
#define WRAW 128
#define HRAW 128
#define CR 28
#define CR2 784
#define FAN 25088          // CFEAT*CR2
#define KB 384             // KOBJ*B

// ---- output offsets (floats, concatenated in reference return order) ----
#define OFF_PROB   0
#define OFF_AREA   8192
#define OFF_CFEW   16384
#define OFF_PFEW   16768
#define OFF_BXF    17152
#define OFF_BYF    17536
#define OFF_BWF    17920
#define OFF_BHF    18304
#define OFF_BMASK  18688
#define OFF_BMASKN 6310144
#define OFF_BIMG   12601600
#define OFF_ZWS    18893056
#define OFF_ZWK    18896128
#define OFF_ZIS    18899200
#define OFF_ZIK    18911488

// ---- workspace offsets (floats) ----
#define WS_SMALL 32768                     // KB*1568 = 602112 floats

// ---- scratch inside big_mask output region (6.29M floats, overwritten later) ----
#define SCR_PART 0                         // FSPLIT*KB*64 = 688128 floats
#define SCR_WT   2752512                   // FAN*64 bf16 = 802816 floats (fragment-ordered)

// ---- enc GEMM tiling (MFMA v9: 4 K-chunks/block, double-buffered sampling) ----
#define FSPLIT 28
#define FPB 896            // K per block = 4 chunks x 224
#define CHK 224
#define NCH 4
#define MKB 16             // kb rows per block
#define KSTR 232           // LDS row stride in bf16 elems
#define TAPN (MKB*28)      // 448 tap entries per axis

typedef __attribute__((ext_vector_type(8))) short bfrag;    // 8 bf16 (4 VGPRs)
typedef __attribute__((ext_vector_type(4))) float f32x4;

__device__ __forceinline__ float sigm(float x){ return 1.0f/(1.0f+expf(-x)); }
__device__ __forceinline__ float softpl(float x){ return fmaxf(x,0.0f) + log1pf(expf(-fabsf(x))); }
__device__ __forceinline__ float ftanh(float x){
  float t = __expf(2.0f*x);
  return 1.0f - __fdividef(2.0f, t + 1.0f);
}
__device__ __forceinline__ unsigned short f2bf(float f){   // RNE f32->bf16
  unsigned u = __float_as_uint(f);
  unsigned r = u + 0x7FFFu + ((u >> 16) & 1u);
  return (unsigned short)(r >> 16);
}
__device__ __forceinline__ unsigned okey(float f){
  unsigned b = __float_as_uint(f);
  return b ^ ((b & 0x80000000u) ? 0xFFFFFFFFu : 0x80000000u);
}

// K0 (merged): blocks [0,784) = wconv (wenc f32 -> bf16 in MFMA B-fragment order);
// blocks [784,816) = maps + rank top-48 + gather.
// wt index = (((fsc*7 + s)*4 + t)*64 + lane)*8 ; d = t*16+(lane&15), k = fsc*224+s*32+(lane>>4)*8
__global__ __launch_bounds__(256) void prep_kernel(
    const float* __restrict__ wenc, unsigned short* __restrict__ wt,
    const float* __restrict__ logit, const float* __restrict__ zmu,
    const float* __restrict__ zstd, const float* __restrict__ zeps,
    const float* __restrict__ wz, const float* __restrict__ bz,
    float* __restrict__ out){
  __shared__ __align__(16) unsigned su[NBOX];
  if (blockIdx.x < 784){
    const int gid = blockIdx.x*256 + threadIdx.x;   // 200704 total
    const int lane = gid & 63;
    const int rest = gid >> 6;
    const int t = rest & 3;
    const int rest2 = rest >> 2;         // fsc*7 + s
    const int s = rest2 % 7;
    const int fsc = rest2 / 7;
    const int d = t*16 + (lane & 15);
    const int k0 = fsc*CHK + s*32 + (lane >> 4)*8;
    const float* src = wenc + (size_t)d*FAN + k0;
    float4 a = *(const float4*)src;
    float4 b = *(const float4*)(src + 4);
    unsigned long long p0 = (unsigned long long)f2bf(a.x)
      | ((unsigned long long)f2bf(a.y) << 16)
      | ((unsigned long long)f2bf(a.z) << 32)
      | ((unsigned long long)f2bf(a.w) << 48);
    unsigned long long p1 = (unsigned long long)f2bf(b.x)
      | ((unsigned long long)f2bf(b.y) << 16)
      | ((unsigned long long)f2bf(b.z) << 32)
      | ((unsigned long long)f2bf(b.w) << 48);
    unsigned short* dst = wt + (size_t)gid*8;
    *(unsigned long long*)dst       = p0;
    *(unsigned long long*)(dst + 4) = p1;
    return;
  }
  const int bid = blockIdx.x - 784;
  const int b  = bid >> 2;
  const int sb = bid & 3;
  const int tid = threadIdx.x;
  #pragma unroll
  for (int u = 0; u < 4; u++){
    int j = tid + u*256;
    su[j] = okey(logit[b*NBOX + j]);
  }
  const int n = sb*256 + tid;
  const int w = n >> 5, h = n & 31;
  float acc0=bz[0], acc1=bz[1], acc2=bz[2], acc3=bz[3];
  #pragma unroll
  for(int z=0; z<ZWD; z++){
    int id = ((b*ZWD + z)*NWD + w)*NHD + h;
    float s = zmu[id] + zstd[id]*zeps[id];
    acc0 += s*wz[0*ZWD+z]; acc1 += s*wz[1*ZWD+z];
    acc2 += s*wz[2*ZWD+z]; acc3 += s*wz[3*ZWD+z];
  }
  float tx=sigm(acc0), ty=sigm(acc1), tw=sigm(acc2), th=sigm(acc3);
  float bx = (128.0f*((float)w + tx))/32.0f;
  float by = (128.0f*((float)h + ty))/32.0f;
  float bwv = 10.0f + 30.0f*tw;
  float bhv = 10.0f + 30.0f*th;
  float lg = logit[b*NBOX + n];
  out[OFF_PROB + b*NBOX + n] = sigm(lg);
  out[OFF_AREA + b*NBOX + n] = bwv*bhv;
  __syncthreads();
  const unsigned ui = su[n];
  const uint4* su4 = (const uint4*)su;
  int rank = 0;
  #pragma unroll 4
  for (int jq = 0; jq < NBOX/4; jq++){
    uint4 v = su4[jq];
    int j = jq*4;
    rank += (v.x > ui || (v.x == ui && j   < n)) ? 1 : 0;
    rank += (v.y > ui || (v.y == ui && j+1 < n)) ? 1 : 0;
    rank += (v.z > ui || (v.z == ui && j+2 < n)) ? 1 : 0;
    rank += (v.w > ui || (v.w == ui && j+3 < n)) ? 1 : 0;
  }
  if (rank < KOBJ){
    out[OFF_CFEW + rank*B + b] = lg;
    out[OFF_PFEW + rank*B + b] = sigm(lg);
    out[OFF_BXF  + rank*B + b] = bx;
    out[OFF_BYF  + rank*B + b] = by;
    out[OFF_BWF  + rank*B + b] = bwv;
    out[OFF_BHF  + rank*B + b] = bhv;
    #pragma unroll
    for(int z=0; z<ZWD; z++){
      int id = ((b*ZWD + z)*NWD + w)*NHD + h;
      float mu = zmu[id], sd = zstd[id];
      out[OFF_ZWS + (rank*B+b)*ZWD + z] = mu + sd*zeps[id];
      out[OFF_ZWK + (rank*B+b)*ZWD + z] = 0.5f*(mu*mu + sd*sd) - logf(sd) - 0.5f;
    }
  }
}

__device__ __forceinline__ void sample_chunk(
    int tid, int fs, int ch, int kb0, const float* __restrict__ feat,
    const float2* wxs, const int2* xos, const float2* wys, const int2* yos,
    unsigned short* cl){
  const int kc0 = fs*FPB + ch*CHK;
  #pragma unroll 2
  for (int u = 0; u < 14; u++){
    int idx = u*256 + tid;
    int rr = idx / CHK, ff = idx - rr*CHK;
    int f = kc0 + ff;
    int c = f / CR2; int p = f - c*CR2;
    int i = p / CR;  int j = p - i*CR;
    const float* img = feat + (size_t)(((kb0+rr) & (B-1))*CFEAT + c)*(WRAW*HRAW);
    float2 wx = wxs[rr*28 + i]; int2 xo = xos[rr*28 + i];
    float2 wy = wys[rr*28 + j]; int2 yo = yos[rr*28 + j];
    float v = (img[xo.x+yo.x]*wy.x + img[xo.x+yo.y]*wy.y)*wx.x
            + (img[xo.y+yo.x]*wy.x + img[xo.y+yo.y]*wy.y)*wx.y;
    cl[rr*KSTR + ff] = f2bf(v);
  }
}

// K2 (v9): tap tables -> 4 K-chunks of {sample(next) || MFMA(cur)} double-buffered;
// B-frags direct from fragment-ordered global weights. acc accumulates across chunks.
__global__ __launch_bounds__(256, 8) void enc_kernel(
    const float* __restrict__ feat, const unsigned short* __restrict__ wt,
    const float* __restrict__ outc, float* __restrict__ part){
  __shared__ __align__(16) unsigned short cl0[MKB*KSTR];
  __shared__ __align__(16) unsigned short cl1[MKB*KSTR];
  __shared__ float2 wxs[TAPN]; __shared__ int2 xos[TAPN];
  __shared__ float2 wys[TAPN]; __shared__ int2 yos[TAPN];
  __shared__ float rAx[MKB], rSx[MKB], rAy[MKB], rSy[MKB];
  const int tid = threadIdx.x;
  const int fs  = blockIdx.x % FSPLIT;
  const int kb0 = (blockIdx.x / FSPLIT) * MKB;
  if (tid < MKB){
    float bx = outc[OFF_BXF + kb0 + tid];
    float by = outc[OFF_BYF + kb0 + tid];
    float bw = outc[OFF_BWF + kb0 + tid];
    float bh = outc[OFF_BHF + kb0 + tid];
    float sx = bw * (1.0f/(float)CR), sy = bh * (1.0f/(float)CR);
    rSx[tid] = sx; rSy[tid] = sy;
    rAx[tid] = bx - 0.5f*bw + 0.5f*sx - 0.5f;
    rAy[tid] = by - 0.5f*bh + 0.5f*sy - 0.5f;
  }
  __syncthreads();
  // tap tables: 448 x-entries then 448 y-entries
  #pragma unroll
  for (int it = 0; it < 4; it++){
    int idx = it*256 + tid;
    if (idx < 2*TAPN){
      int isy = idx >= TAPN;
      int q = idx - (isy ? TAPN : 0);
      int rr = q / 28, i = q - rr*28;
      float A = isy ? rAy[rr] : rAx[rr];
      float S = isy ? rSy[rr] : rSx[rr];
      float x = fmaf((float)i, S, A);
      float x0f = floorf(x); int x0 = (int)x0f;
      float w1 = x - x0f, w0 = 1.0f - w1;
      if ((unsigned)x0     >= WRAW) w0 = 0.f;
      if ((unsigned)(x0+1) >= WRAW) w1 = 0.f;
      int c0 = min(max(x0,0),WRAW-1), c1 = min(max(x0+1,0),WRAW-1);
      if (isy){ wys[q] = make_float2(w0,w1); yos[q] = make_int2(c0, c1); }
      else    { wxs[q] = make_float2(w0,w1); xos[q] = make_int2(c0*HRAW, c1*HRAW); }
    }
  }
  __syncthreads();
  const int lane = tid & 63, wv = tid >> 6;
  const int lr = lane & 15, lg = lane >> 4;
  f32x4 acc = {0.f,0.f,0.f,0.f};
  sample_chunk(tid, fs, 0, kb0, feat, wxs, xos, wys, yos, cl0);
  __syncthreads();
  #pragma unroll
  for (int ch = 0; ch < NCH; ch++){
    unsigned short* cur = (ch & 1) ? cl1 : cl0;
    unsigned short* nxt = (ch & 1) ? cl0 : cl1;
    if (ch < NCH-1)
      sample_chunk(tid, fs, ch+1, kb0, feat, wxs, xos, wys, yos, nxt);
    const unsigned short* arow  = &cur[lr*KSTR + lg*8];
    const unsigned short* bbase = wt + (size_t)(fs*NCH + ch)*14336 + wv*512 + lane*8;
    #pragma unroll
    for (int s = 0; s < 7; s++){
      bfrag a = *(const bfrag*)(arow + s*32);
      bfrag b = *(const bfrag*)(bbase + s*2048);
      acc = __builtin_amdgcn_mfma_f32_16x16x32_bf16(a, b, acc, 0, 0, 0);
    }
    __syncthreads();
  }
  float* dst = part + ((size_t)fs*KB + kb0)*64;
  #pragma unroll
  for (int r = 0; r < 4; r++){
    int row = lg*4 + r;                // kb offset
    dst[row*64 + wv*16 + lr] = acc[r]; // d = wv*16 + lr
  }
}

// K3: reduce enc partials (28 slices) + bias -> zi reparam/KL -> dec GEMM + act -> ws_small
__global__ __launch_bounds__(256) void zi_dec_kernel(
    const float* __restrict__ part, const float* __restrict__ benc,
    const float* __restrict__ ieps, const float* __restrict__ wdec,
    const float* __restrict__ bdec, float* __restrict__ out,
    float* __restrict__ ws){
  int kb = blockIdx.x;
  int d = threadIdx.x & 63, seg = threadIdx.x >> 6;
  float s0=0.f, s1=0.f;
  for (int f = seg; f < FSPLIT; f += 8)
    s0 += part[((size_t)f*KB + kb)*64 + d];
  for (int f = seg+4; f < FSPLIT; f += 8)
    s1 += part[((size_t)f*KB + kb)*64 + d];
  __shared__ float red[4][64];
  __shared__ float zs[ZID];
  __shared__ float cf_s;
  red[seg][d] = s0 + s1;
  __syncthreads();
  if (threadIdx.x < ZID){
    int dd = threadIdx.x;
    float mu = benc[dd]     + red[0][dd]     + red[1][dd]     + red[2][dd]     + red[3][dd];
    float pe = benc[ZID+dd] + red[0][ZID+dd] + red[1][ZID+dd] + red[2][ZID+dd] + red[3][ZID+dd];
    float sd = softpl(pe) + 1e-4f;
    float zsv = mu + sd*ieps[kb*ZID + dd];
    out[OFF_ZIS + kb*ZID + dd] = zsv;
    out[OFF_ZIK + kb*ZID + dd] = 0.5f*(mu*mu + sd*sd) - logf(sd) - 0.5f;
    zs[dd] = zsv;
  }
  if (threadIdx.x == 0) cf_s = out[OFF_CFEW + kb];
  __syncthreads();
  float cf = cf_s;
  for (int f = threadIdx.x; f < 2*CR2; f += 256){
    float a = bdec[f];
    #pragma unroll
    for (int q = 0; q < 8; q++){
      float4 w4 = *(const float4*)&wdec[f*ZID + q*4];
      a = fmaf(zs[q*4+0], w4.x, a);
      a = fmaf(zs[q*4+1], w4.y, a);
      a = fmaf(zs[q*4+2], w4.z, a);
      a = fmaf(zs[q*4+3], w4.w, a);
    }
    float v = (f < CR2) ? softpl(a) : sigm(a);
    ws[WS_SMALL + (size_t)kb*(2*CR2) + f] = v*cf;
  }
}

// K4: fused uncrop + compose. One thread per (b, pixel); wr[48] in registers.
__global__ __launch_bounds__(256) void uncrop_compose_kernel(
    const float* __restrict__ ws, float* __restrict__ out){
  const int t = blockIdx.x*256 + threadIdx.x;
  const int b = t >> 14, p = t & 16383;
  const int X = p >> 7, Y = p & 127;
  __shared__ float sAx[KOBJ], sSx[KOBJ], sAy[KOBJ], sSy[KOBJ];
  if (threadIdx.x < KOBJ){
    int k = threadIdx.x;
    float bx = out[OFF_BXF + k*B + b], bw = out[OFF_BWF + k*B + b];
    float by = out[OFF_BYF + k*B + b], bh = out[OFF_BHF + k*B + b];
    float ix = __fdividef((float)CR, bw), iy = __fdividef((float)CR, bh);
    sSx[k] = ix; sAx[k] = (0.5f*bw - bx)*ix - 0.5f;
    sSy[k] = iy; sAy[k] = (0.5f*bh - by)*iy - 0.5f;
  }
  __syncthreads();
  const float xc = (float)X + 0.5f, yc = (float)Y + 0.5f;
  float wr[KOBJ];
  float sum = 0.f;
  #pragma unroll
  for (int k = 0; k < KOBJ; k++){
    float x = fmaf(xc, sSx[k], sAx[k]);
    float y = fmaf(yc, sSy[k], sAy[k]);
    const float* sm = ws + WS_SMALL + (size_t)(k*B + b)*(2*CR2);
    float x0f = floorf(x), y0f = floorf(y);
    int x0 = (int)x0f, y0 = (int)y0f;
    float wx1 = x - x0f, wx0 = 1.0f - wx1;
    float wy1 = y - y0f, wy0 = 1.0f - wy1;
    if ((unsigned)x0     >= CR) wx0 = 0.f;
    if ((unsigned)(x0+1) >= CR) wx1 = 0.f;
    if ((unsigned)y0     >= CR) wy0 = 0.f;
    if ((unsigned)(y0+1) >= CR) wy1 = 0.f;
    int x0c = min(max(x0,0),CR-1), x1c = min(max(x0+1,0),CR-1);
    int y0c = min(max(y0,0),CR-1), y1c = min(max(y0+1,0),CR-1);
    const float* r0 = sm + x0c*CR;
    const float* r1 = sm + x1c*CR;
    float v0 = (r0[y0c]*wy0 + r0[y1c]*wy1)*wx0 + (r1[y0c]*wy0 + r1[y1c]*wy1)*wx1;
    const float* q0 = r0 + CR2;
    const float* q1 = r1 + CR2;
    float v1 = (q0[y0c]*wy0 + q0[y1c]*wy1)*wx0 + (q1[y0c]*wy0 + q1[y1c]*wy1)*wx1;
    wr[k] = v0; sum += v0;
    out[OFF_BIMG + (size_t)(k*B + b)*16384 + p] = v1;
  }
  float th = ftanh(sum);
  float inv = 1.0f / fmaxf(sum, 1e-6f);
  #pragma unroll
  for (int k = 0; k < KOBJ; k++){
    size_t o = (size_t)(k*B + b)*16384 + p;
    out[OFF_BMASK  + o] = th * (wr[k] * inv);
    out[OFF_BMASKN + o] = ftanh(wr[k]);
  }
}

extern "C" void kernel_launch(void* const* d_in, const int* in_sizes, int n_in,
                              void* d_out, int out_size, void* d_ws, size_t ws_size,
                              hipStream_t stream) {
  (void)in_sizes; (void)n_in; (void)out_size; (void)ws_size;
  const float* logit = (const float*)d_in[0];
  const float* zmu   = (const float*)d_in[1];
  const float* zstd  = (const float*)d_in[2];
  const float* zeps  = (const float*)d_in[3];
  const float* ieps  = (const float*)d_in[4];
  const float* feat  = (const float*)d_in[5];
  const float* wz    = (const float*)d_in[6];
  const float* bz    = (const float*)d_in[7];
  const float* wenc  = (const float*)d_in[8];
  const float* benc  = (const float*)d_in[9];
  const float* wdec  = (const float*)d_in[10];
  const float* bdec  = (const float*)d_in[11];
  float* out = (float*)d_out;
  float* ws  = (float*)d_ws;
  float* scr = out + OFF_BMASK;                 // scratch inside big_mask region, overwritten later
  float* part = scr + SCR_PART;                 // 688K floats
  unsigned short* wt = (unsigned short*)(scr + SCR_WT);  // 1.6M bf16, fragment-ordered

  prep_kernel         <<<784 + B*4, 256, 0, stream>>>(wenc, wt, logit, zmu, zstd, zeps, wz, bz, out);
  enc_kernel          <<<(KB/MKB)*FSPLIT, 256, 0, stream>>>(feat, wt, out, part);
  zi_dec_kernel       <<<KB, 256, 0, stream>>>(part, benc, ieps, wdec, bdec, out, ws);
  uncrop_compose_kernel<<<(B*WRAW*HRAW)/256, 256, 0, stream>>>(ws, out);
}

// Round 10
// 92.461 us; speedup vs baseline: 1.4236x; 1.0285x over previous
//
#include <hip/hip_runtime.h>
#include <math.h>

// ---- problem constants ----
#define B 8
#define NWD 32
#define NHD 32
#define NBOX 1024          // NWD*NHD
#define ZWD 8
#define ZID 32
#define KOBJ 48
#define CFEAT 32
#define WRAW 128
#define HRAW 128
#define CR 28
#define CR2 784
#define FAN 25088          // CFEAT*CR2
#define KB 384             // KOBJ*B

// ---- output offsets (floats, concatenated in reference return order) ----
#define OFF_PROB   0
#define OFF_AREA   8192
#define OFF_CFEW   16384
#define OFF_PFEW   16768
#define OFF_BXF    17152
#define OFF_BYF    17536
#define OFF_BWF    17920
#define OFF_BHF    18304
#define OFF_BMASK  18688
#define OFF_BMASKN 6310144
#define OFF_BIMG   12601600
#define OFF_ZWS    18893056
#define OFF_ZWK    18896128
#define OFF_ZIS    18899200
#define OFF_ZIK    18911488

// ---- workspace offsets (floats) ----
#define WS_SMALL 32768                     // KB*1568 = 602112 floats

// ---- scratch inside big_mask output region (6.29M floats, overwritten later) ----
#define SCR_PART 0                         // FSPLIT*KB*64 = 1204224 floats
#define SCR_WT   2752512                   // FAN*64 bf16 = 802816 floats (fragment-ordered)

// ---- enc GEMM tiling (MFMA v10: async-split gather, CHK=128, FSPLIT=49) ----
#define FSPLIT 49
#define FPB 512            // K per block = 4 chunks x 128
#define CHK 128
#define NCH 4
#define MKB 16             // kb rows per block
#define KSTR 152           // LDS row stride in bf16 elems (304B: 16B-aligned, 16-way bank spread)
#define TAPN (MKB*28)      // 448 tap entries per axis

typedef __attribute__((ext_vector_type(8))) short bfrag;    // 8 bf16 (4 VGPRs)
typedef __attribute__((ext_vector_type(4))) float f32x4;

__device__ __forceinline__ float sigm(float x){ return 1.0f/(1.0f+expf(-x)); }
__device__ __forceinline__ float softpl(float x){ return fmaxf(x,0.0f) + log1pf(expf(-fabsf(x))); }
__device__ __forceinline__ float ftanh(float x){
  float t = __expf(2.0f*x);
  return 1.0f - __fdividef(2.0f, t + 1.0f);
}
__device__ __forceinline__ unsigned short f2bf(float f){   // RNE f32->bf16
  unsigned u = __float_as_uint(f);
  unsigned r = u + 0x7FFFu + ((u >> 16) & 1u);
  return (unsigned short)(r >> 16);
}
__device__ __forceinline__ unsigned okey(float f){
  unsigned b = __float_as_uint(f);
  return b ^ ((b & 0x80000000u) ? 0xFFFFFFFFu : 0x80000000u);
}

// K0 (merged): blocks [0,784) = wconv (one block per global k-step ks);
// blocks [784,816) = maps + rank top-48 + gather.
// wt[ (ks*256 + t*64 + lane)*8 ]: d = t*16+(lane&15), k = ks*32+(lane>>4)*8
__global__ __launch_bounds__(256) void prep_kernel(
    const float* __restrict__ wenc, unsigned short* __restrict__ wt,
    const float* __restrict__ logit, const float* __restrict__ zmu,
    const float* __restrict__ zstd, const float* __restrict__ zeps,
    const float* __restrict__ wz, const float* __restrict__ bz,
    float* __restrict__ out){
  __shared__ __align__(16) unsigned su[NBOX];
  if (blockIdx.x < 784){
    const int ks = blockIdx.x;
    const int tid = threadIdx.x;
    const int lane = tid & 63;
    const int t = tid >> 6;
    const int d = t*16 + (lane & 15);
    const int k0 = ks*32 + (lane >> 4)*8;
    const float* src = wenc + (size_t)d*FAN + k0;
    float4 a = *(const float4*)src;
    float4 b = *(const float4*)(src + 4);
    unsigned long long p0 = (unsigned long long)f2bf(a.x)
      | ((unsigned long long)f2bf(a.y) << 16)
      | ((unsigned long long)f2bf(a.z) << 32)
      | ((unsigned long long)f2bf(a.w) << 48);
    unsigned long long p1 = (unsigned long long)f2bf(b.x)
      | ((unsigned long long)f2bf(b.y) << 16)
      | ((unsigned long long)f2bf(b.z) << 32)
      | ((unsigned long long)f2bf(b.w) << 48);
    unsigned short* dst = wt + ((size_t)ks*256 + tid)*8;
    *(unsigned long long*)dst       = p0;
    *(unsigned long long*)(dst + 4) = p1;
    return;
  }
  const int bid = blockIdx.x - 784;
  const int b  = bid >> 2;
  const int sb = bid & 3;
  const int tid = threadIdx.x;
  #pragma unroll
  for (int u = 0; u < 4; u++){
    int j = tid + u*256;
    su[j] = okey(logit[b*NBOX + j]);
  }
  const int n = sb*256 + tid;
  const int w = n >> 5, h = n & 31;
  float acc0=bz[0], acc1=bz[1], acc2=bz[2], acc3=bz[3];
  #pragma unroll
  for(int z=0; z<ZWD; z++){
    int id = ((b*ZWD + z)*NWD + w)*NHD + h;
    float s = zmu[id] + zstd[id]*zeps[id];
    acc0 += s*wz[0*ZWD+z]; acc1 += s*wz[1*ZWD+z];
    acc2 += s*wz[2*ZWD+z]; acc3 += s*wz[3*ZWD+z];
  }
  float tx=sigm(acc0), ty=sigm(acc1), tw=sigm(acc2), th=sigm(acc3);
  float bx = (128.0f*((float)w + tx))/32.0f;
  float by = (128.0f*((float)h + ty))/32.0f;
  float bwv = 10.0f + 30.0f*tw;
  float bhv = 10.0f + 30.0f*th;
  float lg = logit[b*NBOX + n];
  out[OFF_PROB + b*NBOX + n] = sigm(lg);
  out[OFF_AREA + b*NBOX + n] = bwv*bhv;
  __syncthreads();
  const unsigned ui = su[n];
  const uint4* su4 = (const uint4*)su;
  int rank = 0;
  #pragma unroll 4
  for (int jq = 0; jq < NBOX/4; jq++){
    uint4 v = su4[jq];
    int j = jq*4;
    rank += (v.x > ui || (v.x == ui && j   < n)) ? 1 : 0;
    rank += (v.y > ui || (v.y == ui && j+1 < n)) ? 1 : 0;
    rank += (v.z > ui || (v.z == ui && j+2 < n)) ? 1 : 0;
    rank += (v.w > ui || (v.w == ui && j+3 < n)) ? 1 : 0;
  }
  if (rank < KOBJ){
    out[OFF_CFEW + rank*B + b] = lg;
    out[OFF_PFEW + rank*B + b] = sigm(lg);
    out[OFF_BXF  + rank*B + b] = bx;
    out[OFF_BYF  + rank*B + b] = by;
    out[OFF_BWF  + rank*B + b] = bwv;
    out[OFF_BHF  + rank*B + b] = bhv;
    #pragma unroll
    for(int z=0; z<ZWD; z++){
      int id = ((b*ZWD + z)*NWD + w)*NHD + h;
      float mu = zmu[id], sd = zstd[id];
      out[OFF_ZWS + (rank*B+b)*ZWD + z] = mu + sd*zeps[id];
      out[OFF_ZWK + (rank*B+b)*ZWD + z] = 0.5f*(mu*mu + sd*sd) - logf(sd) - 0.5f;
    }
  }
}

// K2 (v10): async-split crop gather + MFMA.
// Per chunk: issue 4 B-frag loads, issue next chunk's 32 gathers into regs,
// MFMA current (gathers stay in flight past the counted vmcnt), then combine+ds_write.
__global__ __launch_bounds__(256, 4) void enc_kernel(
    const float* __restrict__ feat, const unsigned short* __restrict__ wt,
    const float* __restrict__ outc, float* __restrict__ part){
  __shared__ __align__(16) unsigned short cl0[MKB*KSTR];
  __shared__ __align__(16) unsigned short cl1[MKB*KSTR];
  __shared__ float2 wxs[TAPN]; __shared__ int2 xos[TAPN];
  __shared__ float2 wys[TAPN]; __shared__ int2 yos[TAPN];
  __shared__ float rAx[MKB], rSx[MKB], rAy[MKB], rSy[MKB];
  const int tid = threadIdx.x;
  const int fs  = blockIdx.x % FSPLIT;
  const int kb0 = (blockIdx.x / FSPLIT) * MKB;
  if (tid < MKB){
    float bx = outc[OFF_BXF + kb0 + tid];
    float by = outc[OFF_BYF + kb0 + tid];
    float bw = outc[OFF_BWF + kb0 + tid];
    float bh = outc[OFF_BHF + kb0 + tid];
    float sx = bw * (1.0f/(float)CR), sy = bh * (1.0f/(float)CR);
    rSx[tid] = sx; rSy[tid] = sy;
    rAx[tid] = bx - 0.5f*bw + 0.5f*sx - 0.5f;
    rAy[tid] = by - 0.5f*bh + 0.5f*sy - 0.5f;
  }
  __syncthreads();
  // tap tables: 448 x-entries then 448 y-entries
  #pragma unroll
  for (int it = 0; it < 4; it++){
    int idx = it*256 + tid;
    if (idx < 2*TAPN){
      int isy = idx >= TAPN;
      int q = idx - (isy ? TAPN : 0);
      int rr = q / 28, i = q - rr*28;
      float A = isy ? rAy[rr] : rAx[rr];
      float S = isy ? rSy[rr] : rSx[rr];
      float x = fmaf((float)i, S, A);
      float x0f = floorf(x); int x0 = (int)x0f;
      float w1 = x - x0f, w0 = 1.0f - w1;
      if ((unsigned)x0     >= WRAW) w0 = 0.f;
      if ((unsigned)(x0+1) >= WRAW) w1 = 0.f;
      int c0 = min(max(x0,0),WRAW-1), c1 = min(max(x0+1,0),WRAW-1);
      if (isy){ wys[q] = make_float2(w0,w1); yos[q] = make_int2(c0, c1); }
      else    { wxs[q] = make_float2(w0,w1); xos[q] = make_int2(c0*HRAW, c1*HRAW); }
    }
  }
  __syncthreads();
  float raw[8][4];
  int ji[8];
  const int fblk = fs*FPB;
  // ---- GATHER(ch): issue 32 loads into raw[], tap indices into ji[] ----
  #define GATHER(CH) { \
    _Pragma("unroll") \
    for (int u = 0; u < 8; u++){ \
      int idx = u*256 + tid; \
      int rr = idx >> 7, ff = idx & 127; \
      int f = fblk + (CH)*CHK + ff; \
      int c = f / CR2; int p = f - c*CR2; \
      int i = p / CR;  int j = p - i*CR; \
      int ii = rr*28 + i, jj = rr*28 + j; \
      ji[u] = (jj << 16) | ii; \
      int2 xo = xos[ii]; int2 yo = yos[jj]; \
      const float* img = feat + (size_t)((rr & (B-1))*CFEAT + c)*(WRAW*HRAW); \
      raw[u][0] = img[xo.x + yo.x]; \
      raw[u][1] = img[xo.x + yo.y]; \
      raw[u][2] = img[xo.y + yo.x]; \
      raw[u][3] = img[xo.y + yo.y]; \
    } }
  // ---- STORE(dst): combine with tap weights, bf16 into LDS ----
  #define STORE(DST) { \
    _Pragma("unroll") \
    for (int u = 0; u < 8; u++){ \
      int idx = u*256 + tid; \
      int rr = idx >> 7, ff = idx & 127; \
      int ii = ji[u] & 0xffff, jj = ji[u] >> 16; \
      float2 wx = wxs[ii]; float2 wy = wys[jj]; \
      float v = (raw[u][0]*wy.x + raw[u][1]*wy.y)*wx.x \
              + (raw[u][2]*wy.x + raw[u][3]*wy.y)*wx.y; \
      (DST)[rr*KSTR + ff] = f2bf(v); \
    } }
  GATHER(0);
  STORE(cl0);
  __syncthreads();
  const int lane = tid & 63, wv = tid >> 6;
  const int lr = lane & 15, lg = lane >> 4;
  f32x4 acc = {0.f,0.f,0.f,0.f};
  #pragma unroll
  for (int ch = 0; ch < NCH; ch++){
    unsigned short* cur = (ch & 1) ? cl1 : cl0;
    unsigned short* nxt = (ch & 1) ? cl0 : cl1;
    // B-fragment loads FIRST (oldest in vmcnt FIFO -> MFMA waits only on these)
    const unsigned short* bptr = wt + (size_t)(fs*16 + ch*4)*2048 + wv*512 + lane*8;
    bfrag b0 = *(const bfrag*)(bptr);
    bfrag b1 = *(const bfrag*)(bptr + 2048);
    bfrag b2 = *(const bfrag*)(bptr + 4096);
    bfrag b3 = *(const bfrag*)(bptr + 6144);
    if (ch < NCH-1){ GATHER(ch+1); }           // 32 gathers stay in flight
    const unsigned short* arow = &cur[lr*KSTR + lg*8];
    bfrag a0 = *(const bfrag*)(arow);
    bfrag a1 = *(const bfrag*)(arow + 32);
    bfrag a2 = *(const bfrag*)(arow + 64);
    bfrag a3 = *(const bfrag*)(arow + 96);
    acc = __builtin_amdgcn_mfma_f32_16x16x32_bf16(a0, b0, acc, 0, 0, 0);
    acc = __builtin_amdgcn_mfma_f32_16x16x32_bf16(a1, b1, acc, 0, 0, 0);
    acc = __builtin_amdgcn_mfma_f32_16x16x32_bf16(a2, b2, acc, 0, 0, 0);
    acc = __builtin_amdgcn_mfma_f32_16x16x32_bf16(a3, b3, acc, 0, 0, 0);
    if (ch < NCH-1){ STORE(nxt); }
    __syncthreads();
  }
  float* dst = part + ((size_t)fs*KB + kb0)*64;
  #pragma unroll
  for (int r = 0; r < 4; r++){
    int row = lg*4 + r;                // kb offset
    dst[row*64 + wv*16 + lr] = acc[r]; // d = wv*16 + lr
  }
  #undef GATHER
  #undef STORE
}

// K3: reduce enc partials (49 slices) + bias -> zi reparam/KL -> dec GEMM + act -> ws_small
__global__ __launch_bounds__(256) void zi_dec_kernel(
    const float* __restrict__ part, const float* __restrict__ benc,
    const float* __restrict__ ieps, const float* __restrict__ wdec,
    const float* __restrict__ bdec, float* __restrict__ out,
    float* __restrict__ ws){
  int kb = blockIdx.x;
  int d = threadIdx.x & 63, seg = threadIdx.x >> 6;
  float s0=0.f, s1=0.f;
  for (int f = seg; f < FSPLIT; f += 8)
    s0 += part[((size_t)f*KB + kb)*64 + d];
  for (int f = seg+4; f < FSPLIT; f += 8)
    s1 += part[((size_t)f*KB + kb)*64 + d];
  __shared__ float red[4][64];
  __shared__ float zs[ZID];
  __shared__ float cf_s;
  red[seg][d] = s0 + s1;
  __syncthreads();
  if (threadIdx.x < ZID){
    int dd = threadIdx.x;
    float mu = benc[dd]     + red[0][dd]     + red[1][dd]     + red[2][dd]     + red[3][dd];
    float pe = benc[ZID+dd] + red[0][ZID+dd] + red[1][ZID+dd] + red[2][ZID+dd] + red[3][ZID+dd];
    float sd = softpl(pe) + 1e-4f;
    float zsv = mu + sd*ieps[kb*ZID + dd];
    out[OFF_ZIS + kb*ZID + dd] = zsv;
    out[OFF_ZIK + kb*ZID + dd] = 0.5f*(mu*mu + sd*sd) - logf(sd) - 0.5f;
    zs[dd] = zsv;
  }
  if (threadIdx.x == 0) cf_s = out[OFF_CFEW + kb];
  __syncthreads();
  float cf = cf_s;
  for (int f = threadIdx.x; f < 2*CR2; f += 256){
    float a = bdec[f];
    #pragma unroll
    for (int q = 0; q < 8; q++){
      float4 w4 = *(const float4*)&wdec[f*ZID + q*4];
      a = fmaf(zs[q*4+0], w4.x, a);
      a = fmaf(zs[q*4+1], w4.y, a);
      a = fmaf(zs[q*4+2], w4.z, a);
      a = fmaf(zs[q*4+3], w4.w, a);
    }
    float v = (f < CR2) ? softpl(a) : sigm(a);
    ws[WS_SMALL + (size_t)kb*(2*CR2) + f] = v*cf;
  }
}

// K4: fused uncrop + compose. One thread per (b, pixel); wr[48] in registers.
__global__ __launch_bounds__(256) void uncrop_compose_kernel(
    const float* __restrict__ ws, float* __restrict__ out){
  const int t = blockIdx.x*256 + threadIdx.x;
  const int b = t >> 14, p = t & 16383;
  const int X = p >> 7, Y = p & 127;
  __shared__ float sAx[KOBJ], sSx[KOBJ], sAy[KOBJ], sSy[KOBJ];
  if (threadIdx.x < KOBJ){
    int k = threadIdx.x;
    float bx = out[OFF_BXF + k*B + b], bw = out[OFF_BWF + k*B + b];
    float by = out[OFF_BYF + k*B + b], bh = out[OFF_BHF + k*B + b];
    float ix = __fdividef((float)CR, bw), iy = __fdividef((float)CR, bh);
    sSx[k] = ix; sAx[k] = (0.5f*bw - bx)*ix - 0.5f;
    sSy[k] = iy; sAy[k] = (0.5f*bh - by)*iy - 0.5f;
  }
  __syncthreads();
  const float xc = (float)X + 0.5f, yc = (float)Y + 0.5f;
  float wr[KOBJ];
  float sum = 0.f;
  #pragma unroll
  for (int k = 0; k < KOBJ; k++){
    float x = fmaf(xc, sSx[k], sAx[k]);
    float y = fmaf(yc, sSy[k], sAy[k]);
    const float* sm = ws + WS_SMALL + (size_t)(k*B + b)*(2*CR2);
    float x0f = floorf(x), y0f = floorf(y);
    int x0 = (int)x0f, y0 = (int)y0f;
    float wx1 = x - x0f, wx0 = 1.0f - wx1;
    float wy1 = y - y0f, wy0 = 1.0f - wy1;
    if ((unsigned)x0     >= CR) wx0 = 0.f;
    if ((unsigned)(x0+1) >= CR) wx1 = 0.f;
    if ((unsigned)y0     >= CR) wy0 = 0.f;
    if ((unsigned)(y0+1) >= CR) wy1 = 0.f;
    int x0c = min(max(x0,0),CR-1), x1c = min(max(x0+1,0),CR-1);
    int y0c = min(max(y0,0),CR-1), y1c = min(max(y0+1,0),CR-1);
    const float* r0 = sm + x0c*CR;
    const float* r1 = sm + x1c*CR;
    float v0 = (r0[y0c]*wy0 + r0[y1c]*wy1)*wx0 + (r1[y0c]*wy0 + r1[y1c]*wy1)*wx1;
    const float* q0 = r0 + CR2;
    const float* q1 = r1 + CR2;
    float v1 = (q0[y0c]*wy0 + q0[y1c]*wy1)*wx0 + (q1[y0c]*wy0 + q1[y1c]*wy1)*wx1;
    wr[k] = v0; sum += v0;
    out[OFF_BIMG + (size_t)(k*B + b)*16384 + p] = v1;
  }
  float th = ftanh(sum);
  float inv = 1.0f / fmaxf(sum, 1e-6f);
  #pragma unroll
  for (int k = 0; k < KOBJ; k++){
    size_t o = (size_t)(k*B + b)*16384 + p;
    out[OFF_BMASK  + o] = th * (wr[k] * inv);
    out[OFF_BMASKN + o] = ftanh(wr[k]);
  }
}

extern "C" void kernel_launch(void* const* d_in, const int* in_sizes, int n_in,
                              void* d_out, int out_size, void* d_ws, size_t ws_size,
                              hipStream_t stream) {
  (void)in_sizes; (void)n_in; (void)out_size; (void)ws_size;
  const float* logit = (const float*)d_in[0];
  const float* zmu   = (const float*)d_in[1];
  const float* zstd  = (const float*)d_in[2];
  const float* zeps  = (const float*)d_in[3];
  const float* ieps  = (const float*)d_in[4];
  const float* feat  = (const float*)d_in[5];
  const float* wz    = (const float*)d_in[6];
  const float* bz    = (const float*)d_in[7];
  const float* wenc  = (const float*)d_in[8];
  const float* benc  = (const float*)d_in[9];
  const float* wdec  = (const float*)d_in[10];
  const float* bdec  = (const float*)d_in[11];
  float* out = (float*)d_out;
  float* ws  = (float*)d_ws;
  float* scr = out + OFF_BMASK;                 // scratch inside big_mask region, overwritten later
  float* part = scr + SCR_PART;                 // 1.2M floats
  unsigned short* wt = (unsigned short*)(scr + SCR_WT);  // 1.6M bf16, k-step-ordered fragments

  prep_kernel         <<<784 + B*4, 256, 0, stream>>>(wenc, wt, logit, zmu, zstd, zeps, wz, bz, out);
  enc_kernel          <<<(KB/MKB)*FSPLIT, 256, 0, stream>>>(feat, wt, out, part);
  zi_dec_kernel       <<<KB, 256, 0, stream>>>(part, benc, ieps, wdec, bdec, out, ws);
  uncrop_compose_kernel<<<(B*WRAW*HRAW)/256, 256, 0, stream>>>(ws, out);
}